// Round 1
// baseline (1118.174 us; speedup 1.0000x reference)
//
#include <hip/hip_runtime.h>
#include <math.h>

#define Bb 64
#define Tt 512
#define Dd 256
#define Nn 1024
#define NROWS 32768

// d_out layout (floats)
#define OUT_SOM 0L
#define OUT_SCAL 8388608L
#define OUT_Q 8388613L
#define OUT_BMU 41943045L

// ws layout (floats)
// 0        nt [256][1024]
// 262144   nnorm [1024]
// 263168   srow [32768]
// 295936   colsum [1024]
// 296960   scal [4] : kl, div, ts, nb
// 296964   bmu_i [32768] ints

static __device__ __forceinline__ float block_reduce_sum(float v, float* sb) {
#pragma unroll
  for (int o = 32; o > 0; o >>= 1) v += __shfl_down(v, o, 64);
  const int lane = threadIdx.x & 63, w = threadIdx.x >> 6;
  if (lane == 0) sb[w] = v;
  __syncthreads();
  return (threadIdx.x == 0) ? (sb[0] + sb[1] + sb[2] + sb[3]) : 0.0f;
}

// ---- K0a: transpose nodes -> nt[d][j], node norms ----
__global__ __launch_bounds__(256) void k_prep(const float* __restrict__ nodes,
                                              float* __restrict__ nt,
                                              float* __restrict__ nnorm) {
  __shared__ float sb[4];
  const int j = blockIdx.x, d = threadIdx.x;
  const float v = nodes[j * Dd + d];
  nt[(long)d * Nn + j] = v;
  const float tot = block_reduce_sum(v * v, sb);
  if (threadIdx.x == 0) nnorm[j] = tot;
}

// ---- K0b: diversity = sum over 1024^2 pairs of dist ----
__global__ __launch_bounds__(256) void k_div(const float* __restrict__ nodes,
                                             const float* __restrict__ nt,
                                             const float* __restrict__ nnorm,
                                             float* __restrict__ scal) {
  __shared__ float ni[4][Dd];
  __shared__ float sb[4];
  const int tid = threadIdx.x;
  const int i0 = blockIdx.x * 4;
#pragma unroll
  for (int r = 0; r < 4; ++r) ni[r][tid] = nodes[(i0 + r) * Dd + tid];
  __syncthreads();
  float acc[4][4];
#pragma unroll
  for (int r = 0; r < 4; ++r)
#pragma unroll
    for (int jj = 0; jj < 4; ++jj) acc[r][jj] = 0.f;
  for (int d = 0; d < Dd; ++d) {
    float nj[4];
#pragma unroll
    for (int jj = 0; jj < 4; ++jj) nj[jj] = nt[(long)d * Nn + tid + 256 * jj];
#pragma unroll
    for (int r = 0; r < 4; ++r) {
      const float s = ni[r][d];
#pragma unroll
      for (int jj = 0; jj < 4; ++jj) acc[r][jj] = fmaf(s, nj[jj], acc[r][jj]);
    }
  }
  float sum = 0.f;
#pragma unroll
  for (int r = 0; r < 4; ++r) {
#pragma unroll
    for (int jj = 0; jj < 4; ++jj) {
      const float d2 = nnorm[i0 + r] + nnorm[tid + 256 * jj] - 2.f * acc[r][jj];
      sum += sqrtf(fmaxf(d2, 0.f));
    }
  }
  const float tot = block_reduce_sum(sum, sb);
  if (tid == 0) atomicAdd(&scal[1], tot);
}

// ---- K1: distance GEMM strip: 64 rows x 1024 cols per block ----
__global__ __launch_bounds__(256) void k_dist(
    const float* __restrict__ z, const float* __restrict__ nt,
    const float* __restrict__ nnorm, float* __restrict__ qout,
    float* __restrict__ srow, float* __restrict__ bmuf, int* __restrict__ bmui) {
  __shared__ float zt[Dd][65];
  __shared__ float rs4[4][64];
  __shared__ unsigned long long cand[4][64];
  const int tid = threadIdx.x, lane = tid & 63, wave = tid >> 6;
  const long row0 = (long)blockIdx.x * 64;

  // stage scaled z strip, transposed
  for (int k = 0; k < 64; ++k) {
    const int t = (int)((row0 + k) & (Tt - 1));
    const float tw = powf(0.9f, (float)(Tt - 1 - t));
    zt[tid][k] = z[(row0 + k) * Dd + tid] * tw;
  }
  __syncthreads();

  float zn = 0.f;
  for (int d = 0; d < Dd; ++d) {
    const float v = zt[d][lane];
    zn = fmaf(v, v, zn);
  }

  const long myrow = row0 + lane;
  float rsum = 0.f;
  unsigned long long best = ~0ull;
  const int j0w = wave * 256;

  for (int chunk = 0; chunk < 16; ++chunk) {
    const int j0 = j0w + chunk * 16;
    float acc[16];
#pragma unroll
    for (int i = 0; i < 16; ++i) acc[i] = 0.f;
    const float* ntp = nt + j0;
    for (int d = 0; d < Dd; ++d) {
      const float zv = zt[d][lane];
      const float4 a = ((const float4*)ntp)[0];
      const float4 b = ((const float4*)ntp)[1];
      const float4 c = ((const float4*)ntp)[2];
      const float4 e = ((const float4*)ntp)[3];
      ntp += Nn;
      acc[0] = fmaf(zv, a.x, acc[0]);
      acc[1] = fmaf(zv, a.y, acc[1]);
      acc[2] = fmaf(zv, a.z, acc[2]);
      acc[3] = fmaf(zv, a.w, acc[3]);
      acc[4] = fmaf(zv, b.x, acc[4]);
      acc[5] = fmaf(zv, b.y, acc[5]);
      acc[6] = fmaf(zv, b.z, acc[6]);
      acc[7] = fmaf(zv, b.w, acc[7]);
      acc[8] = fmaf(zv, c.x, acc[8]);
      acc[9] = fmaf(zv, c.y, acc[9]);
      acc[10] = fmaf(zv, c.z, acc[10]);
      acc[11] = fmaf(zv, c.w, acc[11]);
      acc[12] = fmaf(zv, e.x, acc[12]);
      acc[13] = fmaf(zv, e.y, acc[13]);
      acc[14] = fmaf(zv, e.z, acc[14]);
      acc[15] = fmaf(zv, e.w, acc[15]);
    }
#pragma unroll
    for (int jj = 0; jj < 16; ++jj) {
      const int j = j0 + jj;
      const float d2 = zn + nnorm[j] - 2.f * acc[jj];
      const float dist = sqrtf(fmaxf(d2, 0.f));
      const float qr = 1.f / (1.f + dist);
      qout[myrow * Nn + j] = qr;
      rsum += qr;
      const unsigned long long pk =
          ((unsigned long long)__float_as_uint(dist) << 32) | (unsigned int)j;
      best = pk < best ? pk : best;
    }
  }
  rs4[wave][lane] = rsum;
  cand[wave][lane] = best;
  __syncthreads();
  if (wave == 0) {
    const float s = rs4[0][lane] + rs4[1][lane] + rs4[2][lane] + rs4[3][lane];
    srow[myrow] = s;
    const unsigned long long m0 = cand[0][lane] < cand[1][lane] ? cand[0][lane] : cand[1][lane];
    const unsigned long long m1 = cand[2][lane] < cand[3][lane] ? cand[2][lane] : cand[3][lane];
    const unsigned long long m = m0 < m1 ? m0 : m1;
    const int bj = (int)(unsigned int)(m & 0xffffffffull);
    bmuf[myrow] = (float)bj;
    bmui[myrow] = bj;
  }
}

// ---- K2: normalize q rows in place, accumulate column sums of q^2 ----
__global__ __launch_bounds__(256) void k_norm(float* __restrict__ q,
                                              const float* __restrict__ srow,
                                              float* __restrict__ colsum) {
  const int tid = threadIdx.x;
  const long r0 = (long)blockIdx.x * 16;
  float cs[4] = {0.f, 0.f, 0.f, 0.f};
  for (int r = 0; r < 16; ++r) {
    const long row = r0 + r;
    const float inv = 1.f / srow[row];
#pragma unroll
    for (int j = 0; j < 4; ++j) {
      const long idx = row * Nn + tid + 256 * j;
      const float v = q[idx] * inv;
      q[idx] = v;
      cs[j] = fmaf(v, v, cs[j]);
    }
  }
#pragma unroll
  for (int j = 0; j < 4; ++j) atomicAdd(&colsum[tid + 256 * j], cs[j]);
}

// ---- K3: p + KL ----
__global__ __launch_bounds__(256) void k_kl(const float* __restrict__ q,
                                            const float* __restrict__ colsum,
                                            float* __restrict__ scal) {
  __shared__ float csh[Nn];
  __shared__ float sb[4];
  const int tid = threadIdx.x, lane = tid & 63, wave = tid >> 6;
#pragma unroll
  for (int j = 0; j < 4; ++j) csh[tid + 256 * j] = colsum[tid + 256 * j];
  __syncthreads();
  const long r0 = (long)blockIdx.x * 16;
  float klp = 0.f;
  for (int rr = 0; rr < 4; ++rr) {
    const long row = r0 + rr * 4 + wave;
    float qv[16], u[16], s = 0.f;
#pragma unroll
    for (int j = 0; j < 16; ++j) {
      const int col = lane + 64 * j;
      const float t = q[row * Nn + col];
      qv[j] = t;
      const float uu = t * t / csh[col];
      u[j] = uu;
      s += uu;
    }
#pragma unroll
    for (int o = 1; o < 64; o <<= 1) s += __shfl_xor(s, o, 64);
    const float invS = 1.f / s;
#pragma unroll
    for (int j = 0; j < 16; ++j) {
      const float p = u[j] * invS;
      klp += p * (__logf(p) - __logf(qv[j]));
    }
  }
  const float tot = block_reduce_sum(klp, sb);
  if (tid == 0) atomicAdd(&scal[0], tot);
}

// ---- K4: som_z + time smooth ----
__global__ __launch_bounds__(256) void k_som(const float* __restrict__ z,
                                             const float* __restrict__ nodes,
                                             const int* __restrict__ bmui,
                                             float* __restrict__ som,
                                             float* __restrict__ scal) {
  __shared__ float sb[4];
  const int tid = threadIdx.x;
  const long r0 = (long)blockIdx.x * 16;
  float ts = 0.f, zp = 0.f;
  if ((r0 & (Tt - 1)) > 0) zp = z[(r0 - 1) * Dd + tid];
  for (int r = 0; r < 16; ++r) {
    const long row = r0 + r;
    const float zc = z[row * Dd + tid];
    const float nv = nodes[(long)bmui[row] * Dd + tid];
    som[row * Dd + tid] = zc + 0.1f * (nv - zc);
    if ((row & (Tt - 1)) > 0) {
      const float dd = zc - zp;
      ts = fmaf(dd, dd, ts);
    }
    zp = zc;
  }
  const float tot = block_reduce_sum(ts, sb);
  if (tid == 0) atomicAdd(&scal[2], tot);
}

// ---- K5: neighbor loss ----
__global__ __launch_bounds__(256) void k_nb(const int* __restrict__ bmui,
                                            float* __restrict__ scal) {
  __shared__ float sb[4];
  const int idx = blockIdx.x * 256 + threadIdx.x;
  float s = 0.f;
  if (idx < Bb * (Tt - 1)) {
    const int b = idx / (Tt - 1);
    const int k = idx - b * (Tt - 1);
    const long row = (long)b * Tt + k;
    const int b1 = bmui[row], b2 = bmui[row + 1];
    s = (float)(abs((b1 >> 5) - (b2 >> 5)) + abs((b1 & 31) - (b2 & 31)));
  }
  const float tot = block_reduce_sum(s, sb);
  if (threadIdx.x == 0) atomicAdd(&scal[3], tot);
}

// ---- K6: final scalars ----
__global__ void k_final(const float* __restrict__ scal, float* __restrict__ o) {
  const float kl = scal[0] * (1.f / 32768.f);
  const float dv = -scal[1] * (1.f / (1024.f * 1024.f));
  const float ts = scal[2] * (0.9f / (64.f * 511.f * 256.f));
  const float nb = scal[3] * (1.f / 32704.f);
  o[0] = kl + 0.5f * dv + 0.3f * ts + 0.2f * nb;
  o[1] = kl;
  o[2] = dv;
  o[3] = ts;
  o[4] = nb;
}

extern "C" void kernel_launch(void* const* d_in, const int* in_sizes, int n_in,
                              void* d_out, int out_size, void* d_ws, size_t ws_size,
                              hipStream_t stream) {
  const float* z = (const float*)d_in[0];
  const float* nodes = (const float*)d_in[1];
  float* out = (float*)d_out;
  float* ws = (float*)d_ws;

  float* nt = ws;
  float* nnorm = ws + 262144;
  float* srow = ws + 263168;
  float* colsum = ws + 295936;
  float* scal = ws + 296960;
  int* bmui = (int*)(ws + 296964);

  float* som = out + OUT_SOM;
  float* scal_out = out + OUT_SCAL;
  float* qout = out + OUT_Q;
  float* bmuf = out + OUT_BMU;

  // zero colsum + scalar accumulators (contiguous)
  hipMemsetAsync(colsum, 0, (1024 + 4) * sizeof(float), stream);

  k_prep<<<1024, 256, 0, stream>>>(nodes, nt, nnorm);
  k_div<<<256, 256, 0, stream>>>(nodes, nt, nnorm, scal);
  k_dist<<<512, 256, 0, stream>>>(z, nt, nnorm, qout, srow, bmuf, bmui);
  k_norm<<<2048, 256, 0, stream>>>(qout, srow, colsum);
  k_kl<<<2048, 256, 0, stream>>>(qout, colsum, scal);
  k_som<<<2048, 256, 0, stream>>>(z, nodes, bmui, som, scal);
  k_nb<<<128, 256, 0, stream>>>(bmui, scal);
  k_final<<<1, 1, 0, stream>>>(scal, scal_out);
}

// Round 2
// 448.624 us; speedup vs baseline: 2.4925x; 2.4925x over previous
//
#include <hip/hip_runtime.h>
#include <math.h>

#define Bb 64
#define Tt 512
#define Dd 256
#define Nn 1024
#define NROWS 32768

// d_out layout (floats)
#define OUT_SOM 0L
#define OUT_SCAL 8388608L
#define OUT_Q 8388613L
#define OUT_BMU 41943045L

typedef __attribute__((ext_vector_type(8))) short bf16x8;
typedef __attribute__((ext_vector_type(4))) float f32x4;

static __device__ __forceinline__ unsigned short f2bf(float x) {
  unsigned int u = __float_as_uint(x);
  unsigned int r = (u + 0x7fffu + ((u >> 16) & 1u)) >> 16;
  return (unsigned short)r;
}
static __device__ __forceinline__ float bf2f(unsigned short b) {
  return __uint_as_float(((unsigned int)b) << 16);
}

static __device__ __forceinline__ float block_reduce_sum(float v, float* sb) {
#pragma unroll
  for (int o = 32; o > 0; o >>= 1) v += __shfl_down(v, o, 64);
  const int lane = threadIdx.x & 63, w = threadIdx.x >> 6;
  if (lane == 0) sb[w] = v;
  __syncthreads();
  return (threadIdx.x == 0) ? (sb[0] + sb[1] + sb[2] + sb[3]) : 0.0f;
}

// ---- convert z: scale by tw, split to bf16 hi/lo, row norms ----
__global__ __launch_bounds__(256) void k_convz(const float* __restrict__ z,
                                               unsigned short* __restrict__ zhi,
                                               unsigned short* __restrict__ zlo,
                                               float* __restrict__ zn) {
  __shared__ float sb[4];
  const long row = blockIdx.x;
  const int d = threadIdx.x;
  const int t = (int)(row & (Tt - 1));
  const float tw = powf(0.9f, (float)(Tt - 1 - t));
  const float x = z[row * Dd + d] * tw;
  const unsigned short h = f2bf(x);
  const float hf = bf2f(h);
  const unsigned short l = f2bf(x - hf);
  zhi[row * Dd + d] = h;
  zlo[row * Dd + d] = l;
  const float tot = block_reduce_sum(x * x, sb);
  if (d == 0) zn[row] = tot;
}

// ---- convert nodes: transpose fp32 (for k_div), split bf16, norms ----
__global__ __launch_bounds__(256) void k_convn(const float* __restrict__ nodes,
                                               float* __restrict__ nt,
                                               float* __restrict__ nnorm,
                                               unsigned short* __restrict__ nhi,
                                               unsigned short* __restrict__ nlo) {
  __shared__ float sb[4];
  const int j = blockIdx.x, d = threadIdx.x;
  const float v = nodes[j * Dd + d];
  nt[(long)d * Nn + j] = v;
  const unsigned short h = f2bf(v);
  nhi[j * Dd + d] = h;
  nlo[j * Dd + d] = f2bf(v - bf2f(h));
  const float tot = block_reduce_sum(v * v, sb);
  if (threadIdx.x == 0) nnorm[j] = tot;
}

// ---- diversity = sum over 1024^2 pairs of dist ----
__global__ __launch_bounds__(256) void k_div(const float* __restrict__ nodes,
                                             const float* __restrict__ nt,
                                             const float* __restrict__ nnorm,
                                             float* __restrict__ scal) {
  __shared__ float ni[4][Dd];
  __shared__ float sb[4];
  const int tid = threadIdx.x;
  const int i0 = blockIdx.x * 4;
#pragma unroll
  for (int r = 0; r < 4; ++r) ni[r][tid] = nodes[(i0 + r) * Dd + tid];
  __syncthreads();
  float acc[4][4];
#pragma unroll
  for (int r = 0; r < 4; ++r)
#pragma unroll
    for (int jj = 0; jj < 4; ++jj) acc[r][jj] = 0.f;
  for (int d = 0; d < Dd; ++d) {
    float nj[4];
#pragma unroll
    for (int jj = 0; jj < 4; ++jj) nj[jj] = nt[(long)d * Nn + tid + 256 * jj];
#pragma unroll
    for (int r = 0; r < 4; ++r) {
      const float s = ni[r][d];
#pragma unroll
      for (int jj = 0; jj < 4; ++jj) acc[r][jj] = fmaf(s, nj[jj], acc[r][jj]);
    }
  }
  float sum = 0.f;
#pragma unroll
  for (int r = 0; r < 4; ++r) {
#pragma unroll
    for (int jj = 0; jj < 4; ++jj) {
      const float d2 = nnorm[i0 + r] + nnorm[tid + 256 * jj] - 2.f * acc[r][jj];
      sum += sqrtf(fmaxf(d2, 0.f));
    }
  }
  const float tot = block_reduce_sum(sum, sb);
  if (tid == 0) atomicAdd(&scal[1], tot);
}

// ---- MFMA split-bf16 distance GEMM: 128x128 tile, 4 waves ----
__global__ __launch_bounds__(256, 2) void k_gemm(
    const unsigned short* __restrict__ zhi, const unsigned short* __restrict__ zlo,
    const unsigned short* __restrict__ nhi, const unsigned short* __restrict__ nlo,
    const float* __restrict__ zn, const float* __restrict__ nn,
    float* __restrict__ qout, float* __restrict__ part,
    unsigned long long* __restrict__ bmupack) {
  __shared__ __align__(16) unsigned char smem[66048];
  unsigned char* sAhi = smem;
  unsigned char* sAlo = smem + 16384;
  unsigned char* sBhi = smem + 32768;
  unsigned char* sBlo = smem + 49152;
  float* qtile = (float*)smem;  // [128][129] f32, reused after compute

  const int tid = threadIdx.x, lane = tid & 63, wave = tid >> 6;
  const int wr = wave >> 1, wc = wave & 1;
  const int bm = blockIdx.x >> 3, bn = blockIdx.x & 7;
  const long row0 = (long)bm * 128;
  const int col0 = bn * 128;

  uint4 rA[4], rAl[4], rB[4], rBl[4];

  auto loadstep = [&](int kt) {
    const int k0 = kt * 64;
#pragma unroll
    for (int i = 0; i < 4; ++i) {
      const int c = tid + 256 * i;
      const int r = c >> 3, kb = c & 7;
      const long aoff = (row0 + r) * Dd + k0 + kb * 8;
      const long boff = (long)(col0 + r) * Dd + k0 + kb * 8;
      rA[i] = *(const uint4*)(zhi + aoff);
      rAl[i] = *(const uint4*)(zlo + aoff);
      rB[i] = *(const uint4*)(nhi + boff);
      rBl[i] = *(const uint4*)(nlo + boff);
    }
  };
  auto writestep = [&]() {
#pragma unroll
    for (int i = 0; i < 4; ++i) {
      const int c = tid + 256 * i;
      const int r = c >> 3, kb = c & 7;
      const int off = r * 128 + ((kb ^ (r & 7)) << 4);
      *(uint4*)(sAhi + off) = rA[i];
      *(uint4*)(sAlo + off) = rAl[i];
      *(uint4*)(sBhi + off) = rB[i];
      *(uint4*)(sBlo + off) = rBl[i];
    }
  };

  f32x4 acc[4][4];
#pragma unroll
  for (int i = 0; i < 4; ++i)
#pragma unroll
    for (int j = 0; j < 4; ++j) acc[i][j] = (f32x4){0.f, 0.f, 0.f, 0.f};

  loadstep(0);
  writestep();
  __syncthreads();

  const int arow = wr * 64 + (lane & 15);
  const int bcol = wc * 64 + (lane & 15);
  const int kq = lane >> 4;  // 0..3

  for (int kt = 0; kt < 4; ++kt) {
    if (kt < 3) loadstep(kt + 1);
#pragma unroll
    for (int ks = 0; ks < 2; ++ks) {
      const int kb = ks * 4 + kq;
      bf16x8 ah[4], al[4], bh[4], bl[4];
#pragma unroll
      for (int t = 0; t < 4; ++t) {
        const int ra = arow + t * 16;
        const int offa = ra * 128 + ((kb ^ (ra & 7)) << 4);
        ah[t] = *(const bf16x8*)(sAhi + offa);
        al[t] = *(const bf16x8*)(sAlo + offa);
        const int rb = bcol + t * 16;
        const int offb = rb * 128 + ((kb ^ (rb & 7)) << 4);
        bh[t] = *(const bf16x8*)(sBhi + offb);
        bl[t] = *(const bf16x8*)(sBlo + offb);
      }
#pragma unroll
      for (int i = 0; i < 4; ++i)
#pragma unroll
        for (int j = 0; j < 4; ++j) {
          acc[i][j] = __builtin_amdgcn_mfma_f32_16x16x32_bf16(ah[i], bh[j], acc[i][j], 0, 0, 0);
          acc[i][j] = __builtin_amdgcn_mfma_f32_16x16x32_bf16(ah[i], bl[j], acc[i][j], 0, 0, 0);
          acc[i][j] = __builtin_amdgcn_mfma_f32_16x16x32_bf16(al[i], bh[j], acc[i][j], 0, 0, 0);
        }
    }
    __syncthreads();
    if (kt < 3) {
      writestep();
      __syncthreads();
    }
  }

  // epilogue: dist -> q, row sums, argmin; q tile staged in LDS
  float nnv[4];
#pragma unroll
  for (int j = 0; j < 4; ++j) nnv[j] = nn[col0 + wc * 64 + j * 16 + (lane & 15)];

#pragma unroll
  for (int i = 0; i < 4; ++i) {
#pragma unroll
    for (int r = 0; r < 4; ++r) {
      const int lrow = wr * 64 + i * 16 + kq * 4 + r;
      const long grow = row0 + lrow;
      const float znv = zn[grow];
      float rs = 0.f;
      unsigned long long best = ~0ull;
#pragma unroll
      for (int j = 0; j < 4; ++j) {
        const float dot = acc[i][j][r];
        const float d2 = znv + nnv[j] - 2.f * dot;
        const float dist = sqrtf(fmaxf(d2, 0.f));
        const float qr = 1.f / (1.f + dist);
        rs += qr;
        const int col = col0 + wc * 64 + j * 16 + (lane & 15);
        const unsigned long long pk =
            ((unsigned long long)__float_as_uint(dist) << 32) | (unsigned int)col;
        best = pk < best ? pk : best;
        qtile[lrow * 129 + wc * 64 + j * 16 + (lane & 15)] = qr;
      }
#pragma unroll
      for (int m = 1; m < 16; m <<= 1) {
        rs += __shfl_xor(rs, m, 64);
        const unsigned long long o = __shfl_xor(best, m, 64);
        best = o < best ? o : best;
      }
      if ((lane & 15) == 0) {
        part[grow * 16 + bn * 2 + wc] = rs;
        atomicMin(&bmupack[grow], best);
      }
    }
  }
  __syncthreads();
  {
    const int r = tid >> 1, seg = tid & 1;
    const float* src = qtile + r * 129 + seg * 64;
    float* dst = qout + (row0 + r) * Nn + col0 + seg * 64;
#pragma unroll
    for (int i = 0; i < 16; ++i) *(uint4*)(dst + i * 4) = *(const uint4*)(src + i * 4);
  }
}

// ---- unpack bmu ----
__global__ __launch_bounds__(256) void k_unpack(const unsigned long long* __restrict__ bmupack,
                                                int* __restrict__ bmui,
                                                float* __restrict__ bmuf) {
  const int i = blockIdx.x * 256 + threadIdx.x;
  const int j = (int)(unsigned int)(bmupack[i] & 0xffffffffull);
  bmui[i] = j;
  bmuf[i] = (float)j;
}

// ---- normalize q rows (from partial sums), accumulate colsum of q^2 ----
__global__ __launch_bounds__(256) void k_norm(float* __restrict__ q,
                                              const float* __restrict__ part,
                                              float* __restrict__ colsum) {
  __shared__ float inv16[16];
  const int tid = threadIdx.x;
  const long r0 = (long)blockIdx.x * 16;
  if (tid < 16) {
    float s = 0.f;
    const float* p = part + (r0 + tid) * 16;
#pragma unroll
    for (int i = 0; i < 16; ++i) s += p[i];
    inv16[tid] = 1.f / s;
  }
  __syncthreads();
  float cs[4] = {0.f, 0.f, 0.f, 0.f};
  for (int r = 0; r < 16; ++r) {
    const long row = r0 + r;
    const float inv = inv16[r];
#pragma unroll
    for (int j = 0; j < 4; ++j) {
      const long idx = row * Nn + tid + 256 * j;
      const float v = q[idx] * inv;
      q[idx] = v;
      cs[j] = fmaf(v, v, cs[j]);
    }
  }
#pragma unroll
  for (int j = 0; j < 4; ++j) atomicAdd(&colsum[tid + 256 * j], cs[j]);
}

// ---- p + KL ----
__global__ __launch_bounds__(256) void k_kl(const float* __restrict__ q,
                                            const float* __restrict__ colsum,
                                            float* __restrict__ scal) {
  __shared__ float csh[Nn];
  __shared__ float sb[4];
  const int tid = threadIdx.x, lane = tid & 63, wave = tid >> 6;
#pragma unroll
  for (int j = 0; j < 4; ++j) csh[tid + 256 * j] = colsum[tid + 256 * j];
  __syncthreads();
  const long r0 = (long)blockIdx.x * 16;
  float klp = 0.f;
  for (int rr = 0; rr < 4; ++rr) {
    const long row = r0 + rr * 4 + wave;
    float qv[16], u[16], s = 0.f;
#pragma unroll
    for (int j = 0; j < 16; ++j) {
      const int col = lane + 64 * j;
      const float t = q[row * Nn + col];
      qv[j] = t;
      const float uu = t * t / csh[col];
      u[j] = uu;
      s += uu;
    }
#pragma unroll
    for (int o = 1; o < 64; o <<= 1) s += __shfl_xor(s, o, 64);
    const float invS = 1.f / s;
#pragma unroll
    for (int j = 0; j < 16; ++j) {
      const float p = u[j] * invS;
      klp += p * (__logf(p) - __logf(qv[j]));
    }
  }
  const float tot = block_reduce_sum(klp, sb);
  if (tid == 0) atomicAdd(&scal[0], tot);
}

// ---- som_z + time smooth ----
__global__ __launch_bounds__(256) void k_som(const float* __restrict__ z,
                                             const float* __restrict__ nodes,
                                             const int* __restrict__ bmui,
                                             float* __restrict__ som,
                                             float* __restrict__ scal) {
  __shared__ float sb[4];
  const int tid = threadIdx.x;
  const long r0 = (long)blockIdx.x * 16;
  float ts = 0.f, zp = 0.f;
  if ((r0 & (Tt - 1)) > 0) zp = z[(r0 - 1) * Dd + tid];
  for (int r = 0; r < 16; ++r) {
    const long row = r0 + r;
    const float zc = z[row * Dd + tid];
    const float nv = nodes[(long)bmui[row] * Dd + tid];
    som[row * Dd + tid] = zc + 0.1f * (nv - zc);
    if ((row & (Tt - 1)) > 0) {
      const float dd = zc - zp;
      ts = fmaf(dd, dd, ts);
    }
    zp = zc;
  }
  const float tot = block_reduce_sum(ts, sb);
  if (tid == 0) atomicAdd(&scal[2], tot);
}

// ---- neighbor loss ----
__global__ __launch_bounds__(256) void k_nb(const int* __restrict__ bmui,
                                            float* __restrict__ scal) {
  __shared__ float sb[4];
  const int idx = blockIdx.x * 256 + threadIdx.x;
  float s = 0.f;
  if (idx < Bb * (Tt - 1)) {
    const int b = idx / (Tt - 1);
    const int k = idx - b * (Tt - 1);
    const long row = (long)b * Tt + k;
    const int b1 = bmui[row], b2 = bmui[row + 1];
    s = (float)(abs((b1 >> 5) - (b2 >> 5)) + abs((b1 & 31) - (b2 & 31)));
  }
  const float tot = block_reduce_sum(s, sb);
  if (threadIdx.x == 0) atomicAdd(&scal[3], tot);
}

// ---- final scalars ----
__global__ void k_final(const float* __restrict__ scal, float* __restrict__ o) {
  const float kl = scal[0] * (1.f / 32768.f);
  const float dv = -scal[1] * (1.f / (1024.f * 1024.f));
  const float ts = scal[2] * (0.9f / (64.f * 511.f * 256.f));
  const float nb = scal[3] * (1.f / 32704.f);
  o[0] = kl + 0.5f * dv + 0.3f * ts + 0.2f * nb;
  o[1] = kl;
  o[2] = dv;
  o[3] = ts;
  o[4] = nb;
}

// ================= fallback (round-1 fp32 path, small ws) =================
__global__ __launch_bounds__(256) void k_prep_fb(const float* __restrict__ nodes,
                                                 float* __restrict__ nt,
                                                 float* __restrict__ nnorm) {
  __shared__ float sb[4];
  const int j = blockIdx.x, d = threadIdx.x;
  const float v = nodes[j * Dd + d];
  nt[(long)d * Nn + j] = v;
  const float tot = block_reduce_sum(v * v, sb);
  if (threadIdx.x == 0) nnorm[j] = tot;
}

__global__ __launch_bounds__(256) void k_dist_fb(
    const float* __restrict__ z, const float* __restrict__ nt,
    const float* __restrict__ nnorm, float* __restrict__ qout,
    float* __restrict__ srow, float* __restrict__ bmuf, int* __restrict__ bmui) {
  __shared__ float zt[Dd][65];
  __shared__ float rs4[4][64];
  __shared__ unsigned long long cand[4][64];
  const int tid = threadIdx.x, lane = tid & 63, wave = tid >> 6;
  const long row0 = (long)blockIdx.x * 64;
  for (int k = 0; k < 64; ++k) {
    const int t = (int)((row0 + k) & (Tt - 1));
    const float tw = powf(0.9f, (float)(Tt - 1 - t));
    zt[tid][k] = z[(row0 + k) * Dd + tid] * tw;
  }
  __syncthreads();
  float zn = 0.f;
  for (int d = 0; d < Dd; ++d) {
    const float v = zt[d][lane];
    zn = fmaf(v, v, zn);
  }
  const long myrow = row0 + lane;
  float rsum = 0.f;
  unsigned long long best = ~0ull;
  const int j0w = wave * 256;
  for (int chunk = 0; chunk < 16; ++chunk) {
    const int j0 = j0w + chunk * 16;
    float acc[16];
#pragma unroll
    for (int i = 0; i < 16; ++i) acc[i] = 0.f;
    const float* ntp = nt + j0;
    for (int d = 0; d < Dd; ++d) {
      const float zv = zt[d][lane];
      const float4 a = ((const float4*)ntp)[0];
      const float4 b = ((const float4*)ntp)[1];
      const float4 c = ((const float4*)ntp)[2];
      const float4 e = ((const float4*)ntp)[3];
      ntp += Nn;
      acc[0] = fmaf(zv, a.x, acc[0]); acc[1] = fmaf(zv, a.y, acc[1]);
      acc[2] = fmaf(zv, a.z, acc[2]); acc[3] = fmaf(zv, a.w, acc[3]);
      acc[4] = fmaf(zv, b.x, acc[4]); acc[5] = fmaf(zv, b.y, acc[5]);
      acc[6] = fmaf(zv, b.z, acc[6]); acc[7] = fmaf(zv, b.w, acc[7]);
      acc[8] = fmaf(zv, c.x, acc[8]); acc[9] = fmaf(zv, c.y, acc[9]);
      acc[10] = fmaf(zv, c.z, acc[10]); acc[11] = fmaf(zv, c.w, acc[11]);
      acc[12] = fmaf(zv, e.x, acc[12]); acc[13] = fmaf(zv, e.y, acc[13]);
      acc[14] = fmaf(zv, e.z, acc[14]); acc[15] = fmaf(zv, e.w, acc[15]);
    }
#pragma unroll
    for (int jj = 0; jj < 16; ++jj) {
      const int j = j0 + jj;
      const float d2 = zn + nnorm[j] - 2.f * acc[jj];
      const float dist = sqrtf(fmaxf(d2, 0.f));
      const float qr = 1.f / (1.f + dist);
      qout[myrow * Nn + j] = qr;
      rsum += qr;
      const unsigned long long pk =
          ((unsigned long long)__float_as_uint(dist) << 32) | (unsigned int)j;
      best = pk < best ? pk : best;
    }
  }
  rs4[wave][lane] = rsum;
  cand[wave][lane] = best;
  __syncthreads();
  if (wave == 0) {
    const float s = rs4[0][lane] + rs4[1][lane] + rs4[2][lane] + rs4[3][lane];
    srow[myrow] = s;
    const unsigned long long m0 = cand[0][lane] < cand[1][lane] ? cand[0][lane] : cand[1][lane];
    const unsigned long long m1 = cand[2][lane] < cand[3][lane] ? cand[2][lane] : cand[3][lane];
    const unsigned long long m = m0 < m1 ? m0 : m1;
    const int bj = (int)(unsigned int)(m & 0xffffffffull);
    bmuf[myrow] = (float)bj;
    bmui[myrow] = bj;
  }
}

__global__ __launch_bounds__(256) void k_norm_fb(float* __restrict__ q,
                                                 const float* __restrict__ srow,
                                                 float* __restrict__ colsum) {
  const int tid = threadIdx.x;
  const long r0 = (long)blockIdx.x * 16;
  float cs[4] = {0.f, 0.f, 0.f, 0.f};
  for (int r = 0; r < 16; ++r) {
    const long row = r0 + r;
    const float inv = 1.f / srow[row];
#pragma unroll
    for (int j = 0; j < 4; ++j) {
      const long idx = row * Nn + tid + 256 * j;
      const float v = q[idx] * inv;
      q[idx] = v;
      cs[j] = fmaf(v, v, cs[j]);
    }
  }
#pragma unroll
  for (int j = 0; j < 4; ++j) atomicAdd(&colsum[tid + 256 * j], cs[j]);
}

extern "C" void kernel_launch(void* const* d_in, const int* in_sizes, int n_in,
                              void* d_out, int out_size, void* d_ws, size_t ws_size,
                              hipStream_t stream) {
  const float* z = (const float*)d_in[0];
  const float* nodes = (const float*)d_in[1];
  float* out = (float*)d_out;
  unsigned char* ws = (unsigned char*)d_ws;

  float* som = out + OUT_SOM;
  float* scal_out = out + OUT_SCAL;
  float* qout = out + OUT_Q;
  float* bmuf = out + OUT_BMU;

  const size_t NEED = 38281232;
  if (ws_size >= NEED) {
    float* nt = (float*)(ws + 0);
    unsigned short* zhi = (unsigned short*)(ws + 1048576);
    unsigned short* zlo = (unsigned short*)(ws + 17825792);
    unsigned short* nhi = (unsigned short*)(ws + 34603008);
    unsigned short* nlo = (unsigned short*)(ws + 35127296);
    float* zn = (float*)(ws + 35651584);
    float* part = (float*)(ws + 35782656);
    unsigned long long* bmupack = (unsigned long long*)(ws + 37879808);
    int* bmui = (int*)(ws + 38141952);
    float* nnorm = (float*)(ws + 38273024);
    float* colsum = (float*)(ws + 38277120);
    float* scal = (float*)(ws + 38281216);

    hipMemsetAsync(colsum, 0, 4096 + 16, stream);       // colsum + scal
    hipMemsetAsync(bmupack, 0xFF, 262144, stream);

    k_convz<<<32768, 256, 0, stream>>>(z, zhi, zlo, zn);
    k_convn<<<1024, 256, 0, stream>>>(nodes, nt, nnorm, nhi, nlo);
    k_div<<<256, 256, 0, stream>>>(nodes, nt, nnorm, scal);
    k_gemm<<<2048, 256, 0, stream>>>(zhi, zlo, nhi, nlo, zn, nnorm, qout, part, bmupack);
    k_unpack<<<128, 256, 0, stream>>>(bmupack, bmui, bmuf);
    k_norm<<<2048, 256, 0, stream>>>(qout, part, colsum);
    k_kl<<<2048, 256, 0, stream>>>(qout, colsum, scal);
    k_som<<<2048, 256, 0, stream>>>(z, nodes, bmui, som, scal);
    k_nb<<<128, 256, 0, stream>>>(bmui, scal);
    k_final<<<1, 1, 0, stream>>>(scal, scal_out);
  } else {
    float* wsf = (float*)ws;
    float* nt = wsf;
    float* nnorm = wsf + 262144;
    float* srow = wsf + 263168;
    float* colsum = wsf + 295936;
    float* scal = wsf + 296960;
    int* bmui = (int*)(wsf + 296964);

    hipMemsetAsync(colsum, 0, (1024 + 4) * sizeof(float), stream);
    k_prep_fb<<<1024, 256, 0, stream>>>(nodes, nt, nnorm);
    k_div<<<256, 256, 0, stream>>>(nodes, nt, nnorm, scal);
    k_dist_fb<<<512, 256, 0, stream>>>(z, nt, nnorm, qout, srow, bmuf, bmui);
    k_norm_fb<<<2048, 256, 0, stream>>>(qout, srow, colsum);
    k_kl<<<2048, 256, 0, stream>>>(qout, colsum, scal);
    k_som<<<2048, 256, 0, stream>>>(z, nodes, bmui, som, scal);
    k_nb<<<128, 256, 0, stream>>>(bmui, scal);
    k_final<<<1, 1, 0, stream>>>(scal, scal_out);
  }
}

// Round 3
// 298.018 us; speedup vs baseline: 3.7520x; 1.5054x over previous
//
#include <hip/hip_runtime.h>
#include <math.h>

#define Bb 64
#define Tt 512
#define Dd 256
#define Nn 1024
#define NROWS 32768

// d_out layout (floats)
#define OUT_SOM 0L
#define OUT_SCAL 8388608L
#define OUT_Q 8388613L
#define OUT_BMU 41943045L

typedef __attribute__((ext_vector_type(8))) short bf16x8;
typedef __attribute__((ext_vector_type(4))) float f32x4;
typedef unsigned long long u64;

static __device__ __forceinline__ unsigned short f2bf(float x) {
  unsigned int u = __float_as_uint(x);
  unsigned int r = (u + 0x7fffu + ((u >> 16) & 1u)) >> 16;
  return (unsigned short)r;
}
static __device__ __forceinline__ float bf2f(unsigned short b) {
  return __uint_as_float(((unsigned int)b) << 16);
}

static __device__ __forceinline__ float block_reduce_sum(float v, float* sb) {
#pragma unroll
  for (int o = 32; o > 0; o >>= 1) v += __shfl_down(v, o, 64);
  const int lane = threadIdx.x & 63, w = threadIdx.x >> 6;
  if (lane == 0) sb[w] = v;
  __syncthreads();
  return (threadIdx.x == 0) ? (sb[0] + sb[1] + sb[2] + sb[3]) : 0.0f;
}

// ---- convert z: scale by tw, split bf16 hi/lo, row norms. wave per row ----
__global__ __launch_bounds__(256) void k_convz(const float* __restrict__ z,
                                               unsigned short* __restrict__ zhi,
                                               unsigned short* __restrict__ zlo,
                                               float* __restrict__ zn) {
  const int tid = threadIdx.x, lane = tid & 63, w = tid >> 6;
  const long row = (long)blockIdx.x * 4 + w;
  const int t = (int)(row & (Tt - 1));
  const float tw = powf(0.9f, (float)(Tt - 1 - t));
  const float4 v = ((const float4*)(z + row * Dd))[lane];
  float x[4] = {v.x * tw, v.y * tw, v.z * tw, v.w * tw};
  unsigned short h[4], l[4];
  float s = 0.f;
#pragma unroll
  for (int i = 0; i < 4; ++i) {
    h[i] = f2bf(x[i]);
    l[i] = f2bf(x[i] - bf2f(h[i]));
    s = fmaf(x[i], x[i], s);
  }
  *(ushort4*)(zhi + row * Dd + lane * 4) = make_ushort4(h[0], h[1], h[2], h[3]);
  *(ushort4*)(zlo + row * Dd + lane * 4) = make_ushort4(l[0], l[1], l[2], l[3]);
#pragma unroll
  for (int o = 32; o > 0; o >>= 1) s += __shfl_down(s, o, 64);
  if (lane == 0) zn[row] = s;
}

// ---- convert nodes: fp32 transpose (for k_div), split bf16, norms ----
__global__ __launch_bounds__(256) void k_convn(const float* __restrict__ nodes,
                                               float* __restrict__ nt,
                                               float* __restrict__ nnorm,
                                               unsigned short* __restrict__ nhi,
                                               unsigned short* __restrict__ nlo) {
  __shared__ float sb[4];
  const int j = blockIdx.x, d = threadIdx.x;
  const float v = nodes[j * Dd + d];
  nt[(long)d * Nn + j] = v;
  const unsigned short h = f2bf(v);
  nhi[j * Dd + d] = h;
  nlo[j * Dd + d] = f2bf(v - bf2f(h));
  const float tot = block_reduce_sum(v * v, sb);
  if (threadIdx.x == 0) nnorm[j] = tot;
}

// ---- diversity ----
__global__ __launch_bounds__(256) void k_div(const float* __restrict__ nodes,
                                             const float* __restrict__ nt,
                                             const float* __restrict__ nnorm,
                                             float* __restrict__ scal) {
  __shared__ float ni[4][Dd];
  __shared__ float sb[4];
  const int tid = threadIdx.x;
  const int i0 = blockIdx.x * 4;
#pragma unroll
  for (int r = 0; r < 4; ++r) ni[r][tid] = nodes[(i0 + r) * Dd + tid];
  __syncthreads();
  float acc[4][4];
#pragma unroll
  for (int r = 0; r < 4; ++r)
#pragma unroll
    for (int jj = 0; jj < 4; ++jj) acc[r][jj] = 0.f;
  for (int d = 0; d < Dd; ++d) {
    float nj[4];
#pragma unroll
    for (int jj = 0; jj < 4; ++jj) nj[jj] = nt[(long)d * Nn + tid + 256 * jj];
#pragma unroll
    for (int r = 0; r < 4; ++r) {
      const float s = ni[r][d];
#pragma unroll
      for (int jj = 0; jj < 4; ++jj) acc[r][jj] = fmaf(s, nj[jj], acc[r][jj]);
    }
  }
  float sum = 0.f;
#pragma unroll
  for (int r = 0; r < 4; ++r) {
#pragma unroll
    for (int jj = 0; jj < 4; ++jj) {
      const float d2 = nnorm[i0 + r] + nnorm[tid + 256 * jj] - 2.f * acc[r][jj];
      sum += sqrtf(fmaxf(d2, 0.f));
    }
  }
  const float tot = block_reduce_sum(sum, sb);
  if (tid == 0) atomicAdd(&scal[1], tot);
}

// ---- MFMA split-bf16 distance GEMM, global_load_lds double-buffered ----
// tile 128x128, 4 waves, BK=32, 8 K-steps. LDS: 2 x (Ahi|Alo|Bhi|Blo) x 8KB.
__global__ __launch_bounds__(256, 2) void k_gemm(
    const unsigned short* __restrict__ zhi, const unsigned short* __restrict__ zlo,
    const unsigned short* __restrict__ nhi, const unsigned short* __restrict__ nlo,
    const float* __restrict__ zn, const float* __restrict__ nn,
    float* __restrict__ qout, float* __restrict__ part8,
    u64* __restrict__ bmup8) {
  __shared__ __align__(16) unsigned char smem[65536];

  const int tid = threadIdx.x, lane = tid & 63, wave = tid >> 6;
  const int wr = wave >> 1, wc = wave & 1;
  const int rl = lane & 15, kq = lane >> 4;
  const int bm = blockIdx.x & 255, bn = blockIdx.x >> 8;  // same-bm -> same XCD
  const long row0 = (long)bm * 128;
  const int col0 = bn * 128;

  // stage one K-step (BK=32) of all 4 operand tiles into buffer bufsel.
  // LDS linear [128 rows][32 bf16 = 64B]; global k-slot pre-XOR'd so that
  // reads at slot (kq ^ ((row>>1)&3)) return global slot kq (rule #21).
  auto stage = [&](int kt, int bufsel) {
    unsigned char* lb = smem + bufsel * 32768;
#pragma unroll
    for (int i = 0; i < 2; ++i) {
      const int rbase = (i * 4 + wave) * 16;
      const int r = rbase + (lane >> 2);
      const int kb = (lane & 3) ^ ((r >> 1) & 3);
      const long ea = (row0 + r) * Dd + kt * 32 + kb * 8;
      const long eb = (long)(col0 + r) * Dd + kt * 32 + kb * 8;
      const int lo = rbase * 64;
      __builtin_amdgcn_global_load_lds(
          (const __attribute__((address_space(1))) void*)(zhi + ea),
          (__attribute__((address_space(3))) void*)(lb + lo), 16, 0, 0);
      __builtin_amdgcn_global_load_lds(
          (const __attribute__((address_space(1))) void*)(zlo + ea),
          (__attribute__((address_space(3))) void*)(lb + 8192 + lo), 16, 0, 0);
      __builtin_amdgcn_global_load_lds(
          (const __attribute__((address_space(1))) void*)(nhi + eb),
          (__attribute__((address_space(3))) void*)(lb + 16384 + lo), 16, 0, 0);
      __builtin_amdgcn_global_load_lds(
          (const __attribute__((address_space(1))) void*)(nlo + eb),
          (__attribute__((address_space(3))) void*)(lb + 24576 + lo), 16, 0, 0);
    }
  };

  f32x4 acc[4][4];
#pragma unroll
  for (int i = 0; i < 4; ++i)
#pragma unroll
    for (int j = 0; j < 4; ++j) acc[i][j] = (f32x4){0.f, 0.f, 0.f, 0.f};

  stage(0, 0);
  __syncthreads();

  const int sx = (kq ^ ((rl >> 1) & 3)) << 4;  // swizzled 16B slot, lane-const

  for (int kt = 0; kt < 8; ++kt) {
    if (kt < 7) stage(kt + 1, (kt + 1) & 1);
    unsigned char* lb = smem + (kt & 1) * 32768;
    bf16x8 ah[4], al[4], bh[4], bl[4];
#pragma unroll
    for (int t = 0; t < 4; ++t) {
      const int ra = (wr * 64 + t * 16 + rl) * 64 + sx;
      ah[t] = *(const bf16x8*)(lb + ra);
      al[t] = *(const bf16x8*)(lb + 8192 + ra);
      const int rb = (wc * 64 + t * 16 + rl) * 64 + sx;
      bh[t] = *(const bf16x8*)(lb + 16384 + rb);
      bl[t] = *(const bf16x8*)(lb + 24576 + rb);
    }
#pragma unroll
    for (int i = 0; i < 4; ++i)
#pragma unroll
      for (int j = 0; j < 4; ++j) {
        acc[i][j] = __builtin_amdgcn_mfma_f32_16x16x32_bf16(ah[i], bh[j], acc[i][j], 0, 0, 0);
        acc[i][j] = __builtin_amdgcn_mfma_f32_16x16x32_bf16(ah[i], bl[j], acc[i][j], 0, 0, 0);
        acc[i][j] = __builtin_amdgcn_mfma_f32_16x16x32_bf16(al[i], bh[j], acc[i][j], 0, 0, 0);
      }
    __syncthreads();
  }

  // epilogue: dist -> q (scalar dword stores), row-sum + argmin per 16-group
  float* srs = (float*)smem;                    // [128][2]
  u64* sbest = (u64*)(smem + 1024);             // [128][2]
  float nnv[4];
#pragma unroll
  for (int j = 0; j < 4; ++j) nnv[j] = nn[col0 + wc * 64 + j * 16 + rl];

#pragma unroll
  for (int i = 0; i < 4; ++i) {
#pragma unroll
    for (int r = 0; r < 4; ++r) {
      const int lrow = wr * 64 + i * 16 + kq * 4 + r;
      const long grow = row0 + lrow;
      const float znv = zn[grow];
      float rs = 0.f;
      u64 best = ~0ull;
#pragma unroll
      for (int j = 0; j < 4; ++j) {
        const float dot = acc[i][j][r];
        const float d2 = znv + nnv[j] - 2.f * dot;
        const float dist = sqrtf(fmaxf(d2, 0.f));
        const float qr = 1.f / (1.f + dist);
        rs += qr;
        const int col = col0 + wc * 64 + j * 16 + rl;
        const u64 pk = ((u64)__float_as_uint(dist) << 32) | (unsigned int)col;
        best = pk < best ? pk : best;
        qout[grow * Nn + col] = qr;
      }
#pragma unroll
      for (int m = 1; m < 16; m <<= 1) {
        rs += __shfl_xor(rs, m, 64);
        const u64 o = __shfl_xor(best, m, 64);
        best = o < best ? o : best;
      }
      if (rl == 0) {
        srs[lrow * 2 + wc] = rs;
        sbest[lrow * 2 + wc] = best;
      }
    }
  }
  __syncthreads();
  if (tid < 128) {
    const long grow = row0 + tid;
    part8[grow * 8 + bn] = srs[tid * 2] + srs[tid * 2 + 1];
    const u64 a = sbest[tid * 2], b = sbest[tid * 2 + 1];
    bmup8[grow * 8 + bn] = a < b ? a : b;
  }
}

// ---- reduce per-bn bmu candidates ----
__global__ __launch_bounds__(256) void k_unpack(const u64* __restrict__ bmup8,
                                                float* __restrict__ bmuf) {
  const long row = (long)blockIdx.x * 256 + threadIdx.x;
  u64 best = ~0ull;
#pragma unroll
  for (int i = 0; i < 8; ++i) {
    const u64 v = bmup8[row * 8 + i];
    best = v < best ? v : best;
  }
  bmuf[row] = (float)(int)(unsigned int)(best & 0xffffffffull);
}

// ---- normalize q rows (from 8 partial sums), accumulate colsum of q^2 ----
__global__ __launch_bounds__(256) void k_norm(float* __restrict__ q,
                                              const float* __restrict__ part8,
                                              float* __restrict__ colsum) {
  __shared__ float inv16[16];
  const int tid = threadIdx.x;
  const long r0 = (long)blockIdx.x * 16;
  if (tid < 16) {
    float s = 0.f;
    const float* p = part8 + (r0 + tid) * 8;
#pragma unroll
    for (int i = 0; i < 8; ++i) s += p[i];
    inv16[tid] = 1.f / s;
  }
  __syncthreads();
  float cs[4] = {0.f, 0.f, 0.f, 0.f};
  for (int r = 0; r < 16; ++r) {
    const long row = r0 + r;
    const float inv = inv16[r];
#pragma unroll
    for (int j = 0; j < 4; ++j) {
      const long idx = row * Nn + tid + 256 * j;
      const float v = q[idx] * inv;
      q[idx] = v;
      cs[j] = fmaf(v, v, cs[j]);
    }
  }
#pragma unroll
  for (int j = 0; j < 4; ++j) atomicAdd(&colsum[tid + 256 * j], cs[j]);
}

// ---- p + KL ----
__global__ __launch_bounds__(256) void k_kl(const float* __restrict__ q,
                                            const float* __restrict__ colsum,
                                            float* __restrict__ scal) {
  __shared__ float csh[Nn];
  __shared__ float sb[4];
  const int tid = threadIdx.x, lane = tid & 63, wave = tid >> 6;
#pragma unroll
  for (int j = 0; j < 4; ++j) csh[tid + 256 * j] = colsum[tid + 256 * j];
  __syncthreads();
  const long r0 = (long)blockIdx.x * 16;
  float klp = 0.f;
  for (int rr = 0; rr < 4; ++rr) {
    const long row = r0 + rr * 4 + wave;
    float qv[16], u[16], s = 0.f;
#pragma unroll
    for (int j = 0; j < 16; ++j) {
      const int col = lane + 64 * j;
      const float t = q[row * Nn + col];
      qv[j] = t;
      const float uu = t * t / csh[col];
      u[j] = uu;
      s += uu;
    }
#pragma unroll
    for (int o = 1; o < 64; o <<= 1) s += __shfl_xor(s, o, 64);
    const float invS = 1.f / s;
#pragma unroll
    for (int j = 0; j < 16; ++j) {
      const float p = u[j] * invS;
      klp += p * (__logf(p) - __logf(qv[j]));
    }
  }
  const float tot = block_reduce_sum(klp, sb);
  if (tid == 0) atomicAdd(&scal[0], tot);
}

// ---- som_z + time smooth ----
__global__ __launch_bounds__(256) void k_som(const float* __restrict__ z,
                                             const float* __restrict__ nodes,
                                             const float* __restrict__ bmuf,
                                             float* __restrict__ som,
                                             float* __restrict__ scal) {
  __shared__ float sb[4];
  const int tid = threadIdx.x;
  const long r0 = (long)blockIdx.x * 16;
  float ts = 0.f, zp = 0.f;
  if ((r0 & (Tt - 1)) > 0) zp = z[(r0 - 1) * Dd + tid];
  for (int r = 0; r < 16; ++r) {
    const long row = r0 + r;
    const float zc = z[row * Dd + tid];
    const int bi = (int)bmuf[row];
    const float nv = nodes[(long)bi * Dd + tid];
    som[row * Dd + tid] = zc + 0.1f * (nv - zc);
    if ((row & (Tt - 1)) > 0) {
      const float dd = zc - zp;
      ts = fmaf(dd, dd, ts);
    }
    zp = zc;
  }
  const float tot = block_reduce_sum(ts, sb);
  if (tid == 0) atomicAdd(&scal[2], tot);
}

// ---- neighbor loss ----
__global__ __launch_bounds__(256) void k_nb(const float* __restrict__ bmuf,
                                            float* __restrict__ scal) {
  __shared__ float sb[4];
  const int idx = blockIdx.x * 256 + threadIdx.x;
  float s = 0.f;
  if (idx < Bb * (Tt - 1)) {
    const int b = idx / (Tt - 1);
    const int k = idx - b * (Tt - 1);
    const long row = (long)b * Tt + k;
    const int b1 = (int)bmuf[row], b2 = (int)bmuf[row + 1];
    s = (float)(abs((b1 >> 5) - (b2 >> 5)) + abs((b1 & 31) - (b2 & 31)));
  }
  const float tot = block_reduce_sum(s, sb);
  if (threadIdx.x == 0) atomicAdd(&scal[3], tot);
}

// ---- final scalars ----
__global__ void k_final(const float* __restrict__ scal, float* __restrict__ o) {
  const float kl = scal[0] * (1.f / 32768.f);
  const float dv = -scal[1] * (1.f / (1024.f * 1024.f));
  const float ts = scal[2] * (0.9f / (64.f * 511.f * 256.f));
  const float nb = scal[3] * (1.f / 32704.f);
  o[0] = kl + 0.5f * dv + 0.3f * ts + 0.2f * nb;
  o[1] = kl;
  o[2] = dv;
  o[3] = ts;
  o[4] = nb;
}

// ================= fallback (fp32 path, small ws) =================
__global__ __launch_bounds__(256) void k_prep_fb(const float* __restrict__ nodes,
                                                 float* __restrict__ nt,
                                                 float* __restrict__ nnorm) {
  __shared__ float sb[4];
  const int j = blockIdx.x, d = threadIdx.x;
  const float v = nodes[j * Dd + d];
  nt[(long)d * Nn + j] = v;
  const float tot = block_reduce_sum(v * v, sb);
  if (threadIdx.x == 0) nnorm[j] = tot;
}

__global__ __launch_bounds__(256) void k_dist_fb(
    const float* __restrict__ z, const float* __restrict__ nt,
    const float* __restrict__ nnorm, float* __restrict__ qout,
    float* __restrict__ srow, float* __restrict__ bmuf) {
  __shared__ float zt[Dd][65];
  __shared__ float rs4[4][64];
  __shared__ u64 cand[4][64];
  const int tid = threadIdx.x, lane = tid & 63, wave = tid >> 6;
  const long row0 = (long)blockIdx.x * 64;
  for (int k = 0; k < 64; ++k) {
    const int t = (int)((row0 + k) & (Tt - 1));
    const float tw = powf(0.9f, (float)(Tt - 1 - t));
    zt[tid][k] = z[(row0 + k) * Dd + tid] * tw;
  }
  __syncthreads();
  float zns = 0.f;
  for (int d = 0; d < Dd; ++d) {
    const float v = zt[d][lane];
    zns = fmaf(v, v, zns);
  }
  const long myrow = row0 + lane;
  float rsum = 0.f;
  u64 best = ~0ull;
  const int j0w = wave * 256;
  for (int chunk = 0; chunk < 16; ++chunk) {
    const int j0 = j0w + chunk * 16;
    float acc[16];
#pragma unroll
    for (int i = 0; i < 16; ++i) acc[i] = 0.f;
    const float* ntp = nt + j0;
    for (int d = 0; d < Dd; ++d) {
      const float zv = zt[d][lane];
      const float4 a = ((const float4*)ntp)[0];
      const float4 b = ((const float4*)ntp)[1];
      const float4 c = ((const float4*)ntp)[2];
      const float4 e = ((const float4*)ntp)[3];
      ntp += Nn;
      acc[0] = fmaf(zv, a.x, acc[0]); acc[1] = fmaf(zv, a.y, acc[1]);
      acc[2] = fmaf(zv, a.z, acc[2]); acc[3] = fmaf(zv, a.w, acc[3]);
      acc[4] = fmaf(zv, b.x, acc[4]); acc[5] = fmaf(zv, b.y, acc[5]);
      acc[6] = fmaf(zv, b.z, acc[6]); acc[7] = fmaf(zv, b.w, acc[7]);
      acc[8] = fmaf(zv, c.x, acc[8]); acc[9] = fmaf(zv, c.y, acc[9]);
      acc[10] = fmaf(zv, c.z, acc[10]); acc[11] = fmaf(zv, c.w, acc[11]);
      acc[12] = fmaf(zv, e.x, acc[12]); acc[13] = fmaf(zv, e.y, acc[13]);
      acc[14] = fmaf(zv, e.z, acc[14]); acc[15] = fmaf(zv, e.w, acc[15]);
    }
#pragma unroll
    for (int jj = 0; jj < 16; ++jj) {
      const int j = j0 + jj;
      const float d2 = zns + nnorm[j] - 2.f * acc[jj];
      const float dist = sqrtf(fmaxf(d2, 0.f));
      const float qr = 1.f / (1.f + dist);
      qout[myrow * Nn + j] = qr;
      rsum += qr;
      const u64 pk = ((u64)__float_as_uint(dist) << 32) | (unsigned int)j;
      best = pk < best ? pk : best;
    }
  }
  rs4[wave][lane] = rsum;
  cand[wave][lane] = best;
  __syncthreads();
  if (wave == 0) {
    const float s = rs4[0][lane] + rs4[1][lane] + rs4[2][lane] + rs4[3][lane];
    srow[myrow] = s;
    const u64 m0 = cand[0][lane] < cand[1][lane] ? cand[0][lane] : cand[1][lane];
    const u64 m1 = cand[2][lane] < cand[3][lane] ? cand[2][lane] : cand[3][lane];
    const u64 m = m0 < m1 ? m0 : m1;
    bmuf[myrow] = (float)(int)(unsigned int)(m & 0xffffffffull);
  }
}

__global__ __launch_bounds__(256) void k_norm_fb(float* __restrict__ q,
                                                 const float* __restrict__ srow,
                                                 float* __restrict__ colsum) {
  const int tid = threadIdx.x;
  const long r0 = (long)blockIdx.x * 16;
  float cs[4] = {0.f, 0.f, 0.f, 0.f};
  for (int r = 0; r < 16; ++r) {
    const long row = r0 + r;
    const float inv = 1.f / srow[row];
#pragma unroll
    for (int j = 0; j < 4; ++j) {
      const long idx = row * Nn + tid + 256 * j;
      const float v = q[idx] * inv;
      q[idx] = v;
      cs[j] = fmaf(v, v, cs[j]);
    }
  }
#pragma unroll
  for (int j = 0; j < 4; ++j) atomicAdd(&colsum[tid + 256 * j], cs[j]);
}

extern "C" void kernel_launch(void* const* d_in, const int* in_sizes, int n_in,
                              void* d_out, int out_size, void* d_ws, size_t ws_size,
                              hipStream_t stream) {
  const float* z = (const float*)d_in[0];
  const float* nodes = (const float*)d_in[1];
  float* out = (float*)d_out;
  unsigned char* ws = (unsigned char*)d_ws;

  float* som = out + OUT_SOM;
  float* scal_out = out + OUT_SCAL;
  float* qout = out + OUT_Q;
  float* bmuf = out + OUT_BMU;

  const size_t NEED = 37888016;
  if (ws_size >= NEED) {
    unsigned short* zhi = (unsigned short*)(ws + 0);
    unsigned short* zlo = (unsigned short*)(ws + 16777216);
    unsigned short* nhi = (unsigned short*)(ws + 33554432);
    unsigned short* nlo = (unsigned short*)(ws + 34078720);
    float* zn = (float*)(ws + 34603008);
    float* ntpart = (float*)(ws + 34734080);  // nt [256][1024] then part8 [32768][8]
    u64* bmup8 = (u64*)(ws + 35782656);
    float* nnorm = (float*)(ws + 37879808);
    float* colsum = (float*)(ws + 37883904);
    float* scal = (float*)(ws + 37888000);

    hipMemsetAsync(colsum, 0, 4096 + 16, stream);  // colsum + scal

    k_convz<<<8192, 256, 0, stream>>>(z, zhi, zlo, zn);
    k_convn<<<1024, 256, 0, stream>>>(nodes, ntpart, nnorm, nhi, nlo);
    k_div<<<256, 256, 0, stream>>>(nodes, ntpart, nnorm, scal);
    k_gemm<<<2048, 256, 0, stream>>>(zhi, zlo, nhi, nlo, zn, nnorm, qout, ntpart, bmup8);
    k_unpack<<<128, 256, 0, stream>>>(bmup8, bmuf);
    k_norm<<<2048, 256, 0, stream>>>(qout, ntpart, colsum);
    k_kl<<<2048, 256, 0, stream>>>(qout, colsum, scal);
    k_som<<<2048, 256, 0, stream>>>(z, nodes, bmuf, som, scal);
    k_nb<<<128, 256, 0, stream>>>(bmuf, scal);
    k_final<<<1, 1, 0, stream>>>(scal, scal_out);
  } else {
    float* wsf = (float*)ws;
    float* nt = wsf;
    float* nnorm = wsf + 262144;
    float* srow = wsf + 263168;
    float* colsum = wsf + 295936;
    float* scal = wsf + 296960;

    hipMemsetAsync(colsum, 0, (1024 + 4) * sizeof(float), stream);
    k_prep_fb<<<1024, 256, 0, stream>>>(nodes, nt, nnorm);
    k_div<<<256, 256, 0, stream>>>(nodes, nt, nnorm, scal);
    k_dist_fb<<<512, 256, 0, stream>>>(z, nt, nnorm, qout, srow, bmuf);
    k_norm_fb<<<2048, 256, 0, stream>>>(qout, srow, colsum);
    k_kl<<<2048, 256, 0, stream>>>(qout, colsum, scal);
    k_som<<<2048, 256, 0, stream>>>(z, nodes, bmuf, som, scal);
    k_nb<<<128, 256, 0, stream>>>(bmuf, scal);
    k_final<<<1, 1, 0, stream>>>(scal, scal_out);
  }
}

// Round 4
// 277.550 us; speedup vs baseline: 4.0287x; 1.0737x over previous
//
#include <hip/hip_runtime.h>
#include <math.h>

#define Bb 64
#define Tt 512
#define Dd 256
#define Nn 1024
#define NROWS 32768

// d_out layout (floats)
#define OUT_SOM 0L
#define OUT_SCAL 8388608L
#define OUT_Q 8388613L
#define OUT_BMU 41943045L

typedef __attribute__((ext_vector_type(8))) short bf16x8;
typedef __attribute__((ext_vector_type(4))) float f32x4;
typedef unsigned long long u64;
typedef unsigned short ushortT;

static __device__ __forceinline__ unsigned short f2bf(float x) {
  unsigned int u = __float_as_uint(x);
  unsigned int r = (u + 0x7fffu + ((u >> 16) & 1u)) >> 16;
  return (unsigned short)r;
}
static __device__ __forceinline__ float bf2f(unsigned short b) {
  return __uint_as_float(((unsigned int)b) << 16);
}

static __device__ __forceinline__ float block_reduce_sum(float v, float* sb) {
#pragma unroll
  for (int o = 32; o > 0; o >>= 1) v += __shfl_down(v, o, 64);
  const int lane = threadIdx.x & 63, w = threadIdx.x >> 6;
  if (lane == 0) sb[w] = v;
  __syncthreads();
  return (threadIdx.x == 0) ? (sb[0] + sb[1] + sb[2] + sb[3]) : 0.0f;
}

// ============ k_conv: build MFMA-fragment layouts ============
// A-frag (z): per 32-row tile rt: bf16 idx = ((ks*2+g)*4+k8)*128 + r16*8 + e
//   row = rt*32+g*16+r16, k = ks*32+k8*8+e. Tile = 8192 bf16 (16KB).
// B-frag (nodes): per 16-col tile ct: idx = ks*512 + k8*128 + c16*8 + e.
// Lane l of a wave reads a fragment at base + l*8 elements (dwordx4, coalesced).
__global__ __launch_bounds__(256) void k_conv(
    const float* __restrict__ z, const float* __restrict__ nodes,
    ushortT* __restrict__ zhiF, ushortT* __restrict__ zloF, float* __restrict__ zn,
    ushortT* __restrict__ nhiF, ushortT* __restrict__ nloF, float* __restrict__ nnorm) {
  __shared__ float sm[32 * 260];
  const int tid = threadIdx.x;
  if (blockIdx.x < 1024) {
    const int rt = blockIdx.x;
    const long row0 = (long)rt * 32;
    const int r = tid >> 3, c8 = tid & 7;
    const long rowg = row0 + r;
    const int t = (int)(rowg & (Tt - 1));
    const float tw = powf(0.9f, (float)(Tt - 1 - t));
    float nrm = 0.f;
#pragma unroll
    for (int k = 0; k < 8; ++k) {
      const int c4 = c8 + k * 8;
      float4 v = ((const float4*)(z + rowg * Dd))[c4];
      v.x *= tw; v.y *= tw; v.z *= tw; v.w *= tw;
      *(float4*)&sm[r * 260 + c4 * 4] = v;
      nrm += v.x * v.x + v.y * v.y + v.z * v.z + v.w * v.w;
    }
    nrm += __shfl_xor(nrm, 1, 64);
    nrm += __shfl_xor(nrm, 2, 64);
    nrm += __shfl_xor(nrm, 4, 64);
    if (c8 == 0) zn[rowg] = nrm;
    __syncthreads();
    ushort4* oh = (ushort4*)(zhiF + (long)rt * 8192);
    ushort4* ol = (ushort4*)(zloF + (long)rt * 8192);
#pragma unroll
    for (int i = 0; i < 8; ++i) {
      const int o4 = tid + 256 * i;
      const int e4 = (o4 & 1) * 4;
      const int r16 = (o4 >> 1) & 15;
      const int k8 = (o4 >> 5) & 3;
      const int g = (o4 >> 7) & 1;
      const int ks = o4 >> 8;
      const float* p = &sm[(g * 16 + r16) * 260 + ks * 32 + k8 * 8 + e4];
      const float4 v = *(const float4*)p;
      ushort4 h, l;
      h.x = f2bf(v.x); l.x = f2bf(v.x - bf2f(h.x));
      h.y = f2bf(v.y); l.y = f2bf(v.y - bf2f(h.y));
      h.z = f2bf(v.z); l.z = f2bf(v.z - bf2f(h.z));
      h.w = f2bf(v.w); l.w = f2bf(v.w - bf2f(h.w));
      oh[o4] = h;
      ol[o4] = l;
    }
  } else {
    const int ct = blockIdx.x - 1024;  // 0..63
    const int jr = tid >> 4, cg = tid & 15;
    const long nrow = (long)(ct * 16 + jr);
    float nrm = 0.f;
#pragma unroll
    for (int k = 0; k < 4; ++k) {
      const int c4 = cg + k * 16;
      const float4 v = ((const float4*)(nodes + nrow * Dd))[c4];
      *(float4*)&sm[jr * 260 + c4 * 4] = v;
      nrm += v.x * v.x + v.y * v.y + v.z * v.z + v.w * v.w;
    }
    nrm += __shfl_xor(nrm, 1, 64);
    nrm += __shfl_xor(nrm, 2, 64);
    nrm += __shfl_xor(nrm, 4, 64);
    nrm += __shfl_xor(nrm, 8, 64);
    if (cg == 0) nnorm[nrow] = nrm;
    __syncthreads();
    ushort4* oh = (ushort4*)(nhiF + (long)ct * 4096);
    ushort4* ol = (ushort4*)(nloF + (long)ct * 4096);
#pragma unroll
    for (int i = 0; i < 4; ++i) {
      const int o4 = tid + 256 * i;
      const int e4 = (o4 & 1) * 4;
      const int c16 = (o4 >> 1) & 15;
      const int k8 = (o4 >> 5) & 3;
      const int ks = o4 >> 7;
      const float* p = &sm[c16 * 260 + ks * 32 + k8 * 8 + e4];
      const float4 v = *(const float4*)p;
      ushort4 h, l;
      h.x = f2bf(v.x); l.x = f2bf(v.x - bf2f(h.x));
      h.y = f2bf(v.y); l.y = f2bf(v.y - bf2f(h.y));
      h.z = f2bf(v.z); l.z = f2bf(v.z - bf2f(h.z));
      h.w = f2bf(v.w); l.w = f2bf(v.w - bf2f(h.w));
      oh[o4] = h;
      ol[o4] = l;
    }
  }
}

// ============ k_gemm2: 32x1024 per block, reg-only MFMA, fused epilogue ============
__global__ __launch_bounds__(512) void k_gemm2(
    const ushortT* __restrict__ zhiF, const ushortT* __restrict__ zloF,
    const ushortT* __restrict__ nhiF, const ushortT* __restrict__ nloF,
    const float* __restrict__ zn, const float* __restrict__ nn,
    float* __restrict__ qout, float* __restrict__ bmuf, float* __restrict__ colsum) {
  __shared__ float srowS[32][8];
  __shared__ u64 sbmu[32][8];
  __shared__ float sinv[32];
  const int tid = threadIdx.x, lane = tid & 63, w = tid >> 6;
  const int rl = lane & 15, kq = lane >> 4;
  const int rt = blockIdx.x;
  const long row0 = (long)rt * 32;

  const ushortT* Ah = zhiF + (long)rt * 8192;
  const ushortT* Al = zloF + (long)rt * 8192;
  const ushortT* Bh = nhiF + (long)w * 8 * 4096;
  const ushortT* Bl = nloF + (long)w * 8 * 4096;
  const int lo8 = lane * 8;

  f32x4 acc[2][8];
#pragma unroll
  for (int g = 0; g < 2; ++g)
#pragma unroll
    for (int c = 0; c < 8; ++c) acc[g][c] = (f32x4){0.f, 0.f, 0.f, 0.f};

#pragma unroll 1
  for (int ks = 0; ks < 8; ++ks) {
    const bf16x8 ah0 = *(const bf16x8*)(Ah + (ks * 2 + 0) * 512 + lo8);
    const bf16x8 ah1 = *(const bf16x8*)(Ah + (ks * 2 + 1) * 512 + lo8);
    const bf16x8 al0 = *(const bf16x8*)(Al + (ks * 2 + 0) * 512 + lo8);
    const bf16x8 al1 = *(const bf16x8*)(Al + (ks * 2 + 1) * 512 + lo8);
#pragma unroll
    for (int c = 0; c < 8; ++c) {
      const bf16x8 bh = *(const bf16x8*)(Bh + c * 4096 + ks * 512 + lo8);
      const bf16x8 bl = *(const bf16x8*)(Bl + c * 4096 + ks * 512 + lo8);
      acc[0][c] = __builtin_amdgcn_mfma_f32_16x16x32_bf16(ah0, bh, acc[0][c], 0, 0, 0);
      acc[0][c] = __builtin_amdgcn_mfma_f32_16x16x32_bf16(ah0, bl, acc[0][c], 0, 0, 0);
      acc[0][c] = __builtin_amdgcn_mfma_f32_16x16x32_bf16(al0, bh, acc[0][c], 0, 0, 0);
      acc[1][c] = __builtin_amdgcn_mfma_f32_16x16x32_bf16(ah1, bh, acc[1][c], 0, 0, 0);
      acc[1][c] = __builtin_amdgcn_mfma_f32_16x16x32_bf16(ah1, bl, acc[1][c], 0, 0, 0);
      acc[1][c] = __builtin_amdgcn_mfma_f32_16x16x32_bf16(al1, bh, acc[1][c], 0, 0, 0);
    }
  }

  float znv[2][4], nnv[8];
#pragma unroll
  for (int g = 0; g < 2; ++g)
#pragma unroll
    for (int r = 0; r < 4; ++r) znv[g][r] = zn[row0 + g * 16 + kq * 4 + r];
#pragma unroll
  for (int c = 0; c < 8; ++c) nnv[c] = nn[w * 128 + c * 16 + rl];

  float rs[2][4];
  u64 bm[2][4];
#pragma unroll
  for (int g = 0; g < 2; ++g)
#pragma unroll
    for (int r = 0; r < 4; ++r) { rs[g][r] = 0.f; bm[g][r] = ~0ull; }

#pragma unroll
  for (int g = 0; g < 2; ++g)
#pragma unroll
    for (int c = 0; c < 8; ++c)
#pragma unroll
      for (int r = 0; r < 4; ++r) {
        const float dot = acc[g][c][r];
        const float d2 = znv[g][r] + nnv[c] - 2.f * dot;
        const float dist = sqrtf(fmaxf(d2, 0.f));
        const float qv = 1.f / (1.f + dist);
        acc[g][c][r] = qv;
        rs[g][r] += qv;
        const int col = w * 128 + c * 16 + rl;
        const u64 pk = ((u64)__float_as_uint(dist) << 32) | (unsigned int)col;
        bm[g][r] = pk < bm[g][r] ? pk : bm[g][r];
      }
#pragma unroll
  for (int g = 0; g < 2; ++g)
#pragma unroll
    for (int r = 0; r < 4; ++r) {
#pragma unroll
      for (int m = 1; m < 16; m <<= 1) {
        rs[g][r] += __shfl_xor(rs[g][r], m, 64);
        const u64 o = __shfl_xor(bm[g][r], m, 64);
        bm[g][r] = o < bm[g][r] ? o : bm[g][r];
      }
      if (rl == 0) {
        srowS[g * 16 + kq * 4 + r][w] = rs[g][r];
        sbmu[g * 16 + kq * 4 + r][w] = bm[g][r];
      }
    }
  __syncthreads();
  if (tid < 32) {
    float s = 0.f;
    u64 best = ~0ull;
#pragma unroll
    for (int i = 0; i < 8; ++i) {
      s += srowS[tid][i];
      const u64 v = sbmu[tid][i];
      best = v < best ? v : best;
    }
    sinv[tid] = 1.f / s;
    bmuf[row0 + tid] = (float)(int)(unsigned int)(best & 0xffffffffull);
  }
  __syncthreads();

  float inv[2][4];
#pragma unroll
  for (int g = 0; g < 2; ++g)
#pragma unroll
    for (int r = 0; r < 4; ++r) inv[g][r] = sinv[g * 16 + kq * 4 + r];

  float cp[8];
#pragma unroll
  for (int c = 0; c < 8; ++c) cp[c] = 0.f;
#pragma unroll
  for (int g = 0; g < 2; ++g)
#pragma unroll
    for (int c = 0; c < 8; ++c)
#pragma unroll
      for (int r = 0; r < 4; ++r) {
        const float qn = acc[g][c][r] * inv[g][r];
        qout[(row0 + g * 16 + kq * 4 + r) * Nn + w * 128 + c * 16 + rl] = qn;
        cp[c] = fmaf(qn, qn, cp[c]);
      }
#pragma unroll
  for (int c = 0; c < 8; ++c) {
    cp[c] += __shfl_xor(cp[c], 16, 64);
    cp[c] += __shfl_xor(cp[c], 32, 64);
    if (kq == 0) atomicAdd(&colsum[w * 128 + c * 16 + rl], cp[c]);
  }
}

// ============ k_div2: diversity via node fragments ============
__global__ __launch_bounds__(256) void k_div2(
    const ushortT* __restrict__ nhiF, const ushortT* __restrict__ nloF,
    const float* __restrict__ nnorm, float* __restrict__ scal) {
  __shared__ float sb[4];
  const int tid = threadIdx.x, lane = tid & 63, w = tid >> 6;
  const int rl = lane & 15, kq = lane >> 4;
  const int bi = blockIdx.x;
  const int lo8 = lane * 8;

  f32x4 acc[16];
#pragma unroll
  for (int c = 0; c < 16; ++c) acc[c] = (f32x4){0.f, 0.f, 0.f, 0.f};

#pragma unroll 1
  for (int ks = 0; ks < 8; ++ks) {
    const bf16x8 ah = *(const bf16x8*)(nhiF + (long)bi * 4096 + ks * 512 + lo8);
    const bf16x8 al = *(const bf16x8*)(nloF + (long)bi * 4096 + ks * 512 + lo8);
#pragma unroll
    for (int c = 0; c < 16; ++c) {
      const long ct = (long)(w * 16 + c);
      const bf16x8 bh = *(const bf16x8*)(nhiF + ct * 4096 + ks * 512 + lo8);
      const bf16x8 bl = *(const bf16x8*)(nloF + ct * 4096 + ks * 512 + lo8);
      acc[c] = __builtin_amdgcn_mfma_f32_16x16x32_bf16(ah, bh, acc[c], 0, 0, 0);
      acc[c] = __builtin_amdgcn_mfma_f32_16x16x32_bf16(ah, bl, acc[c], 0, 0, 0);
      acc[c] = __builtin_amdgcn_mfma_f32_16x16x32_bf16(al, bh, acc[c], 0, 0, 0);
    }
  }
  float ni[4];
#pragma unroll
  for (int r = 0; r < 4; ++r) ni[r] = nnorm[bi * 16 + kq * 4 + r];
  float dsum = 0.f;
#pragma unroll
  for (int c = 0; c < 16; ++c) {
    const float nj = nnorm[w * 256 + c * 16 + rl];
#pragma unroll
    for (int r = 0; r < 4; ++r) {
      const float d2 = ni[r] + nj - 2.f * acc[c][r];
      dsum += sqrtf(fmaxf(d2, 0.f));
    }
  }
  const float tot = block_reduce_sum(dsum, sb);
  if (tid == 0) atomicAdd(&scal[1], tot);
}

// ============ k_kl: p + KL (1 log per element) ============
__global__ __launch_bounds__(256) void k_kl(const float* __restrict__ q,
                                            const float* __restrict__ colsum,
                                            float* __restrict__ scal) {
  __shared__ float rcs[Nn];
  __shared__ float lcs[Nn];
  __shared__ float sb[4];
  const int tid = threadIdx.x, lane = tid & 63, wave = tid >> 6;
#pragma unroll
  for (int j = 0; j < 4; ++j) {
    const float cs = colsum[tid + 256 * j];
    rcs[tid + 256 * j] = 1.f / cs;
    lcs[tid + 256 * j] = __logf(cs);
  }
  __syncthreads();
  const long r0 = (long)blockIdx.x * 16;
  float klp = 0.f;
  for (int rr = 0; rr < 4; ++rr) {
    const long row = r0 + rr * 4 + wave;
    float s = 0.f, a = 0.f;
#pragma unroll
    for (int j = 0; j < 16; ++j) {
      const int col = lane + 64 * j;
      const float t = q[row * Nn + col];
      const float u = t * t * rcs[col];
      s += u;
      a = fmaf(u, __logf(t) - lcs[col], a);
    }
#pragma unroll
    for (int o = 1; o < 64; o <<= 1) {
      s += __shfl_xor(s, o, 64);
      a += __shfl_xor(a, o, 64);
    }
    if (lane == 0) klp += a / s - __logf(s);  // once per row
  }
  const float tot = block_reduce_sum(klp, sb);
  if (tid == 0) atomicAdd(&scal[0], tot);
}

// ============ k_som + neighbor ============
__global__ __launch_bounds__(256) void k_somnb(const float* __restrict__ z,
                                               const float* __restrict__ nodes,
                                               const float* __restrict__ bmuf,
                                               float* __restrict__ som,
                                               float* __restrict__ scal) {
  __shared__ float sb[4];
  const int tid = threadIdx.x;
  const long r0 = (long)blockIdx.x * 16;
  float ts = 0.f, zp = 0.f;
  if ((r0 & (Tt - 1)) > 0) zp = z[(r0 - 1) * Dd + tid];
  for (int r = 0; r < 16; ++r) {
    const long row = r0 + r;
    const float zc = z[row * Dd + tid];
    const int bi = (int)bmuf[row];
    const float nv = nodes[(long)bi * Dd + tid];
    som[row * Dd + tid] = zc + 0.1f * (nv - zc);
    if ((row & (Tt - 1)) > 0) {
      const float dd = zc - zp;
      ts = fmaf(dd, dd, ts);
    }
    zp = zc;
  }
  const float tts = block_reduce_sum(ts, sb);
  if (tid == 0) atomicAdd(&scal[2], tts);
  float nbv = 0.f;
  if (tid < 16) {
    const long row = r0 + tid;
    if ((row & (Tt - 1)) != (Tt - 1)) {
      const int b1 = (int)bmuf[row], b2 = (int)bmuf[row + 1];
      nbv = (float)(abs((b1 >> 5) - (b2 >> 5)) + abs((b1 & 31) - (b2 & 31)));
    }
  }
  __syncthreads();
  const float tnb = block_reduce_sum(nbv, sb);
  if (tid == 0) atomicAdd(&scal[3], tnb);
}

// ---- final scalars ----
__global__ void k_final(const float* __restrict__ scal, float* __restrict__ o) {
  const float kl = scal[0] * (1.f / 32768.f);
  const float dv = -scal[1] * (1.f / (1024.f * 1024.f));
  const float ts = scal[2] * (0.9f / (64.f * 511.f * 256.f));
  const float nb = scal[3] * (1.f / 32704.f);
  o[0] = kl + 0.5f * dv + 0.3f * ts + 0.2f * nb;
  o[1] = kl;
  o[2] = dv;
  o[3] = ts;
  o[4] = nb;
}

// ================= fallback (fp32 path, small ws) =================
__global__ __launch_bounds__(256) void k_prep_fb(const float* __restrict__ nodes,
                                                 float* __restrict__ nt,
                                                 float* __restrict__ nnorm) {
  __shared__ float sb[4];
  const int j = blockIdx.x, d = threadIdx.x;
  const float v = nodes[j * Dd + d];
  nt[(long)d * Nn + j] = v;
  const float tot = block_reduce_sum(v * v, sb);
  if (threadIdx.x == 0) nnorm[j] = tot;
}

__global__ __launch_bounds__(256) void k_div_fb(const float* __restrict__ nodes,
                                                const float* __restrict__ nt,
                                                const float* __restrict__ nnorm,
                                                float* __restrict__ scal) {
  __shared__ float ni[4][Dd];
  __shared__ float sb[4];
  const int tid = threadIdx.x;
  const int i0 = blockIdx.x * 4;
#pragma unroll
  for (int r = 0; r < 4; ++r) ni[r][tid] = nodes[(i0 + r) * Dd + tid];
  __syncthreads();
  float acc[4][4];
#pragma unroll
  for (int r = 0; r < 4; ++r)
#pragma unroll
    for (int jj = 0; jj < 4; ++jj) acc[r][jj] = 0.f;
  for (int d = 0; d < Dd; ++d) {
    float nj[4];
#pragma unroll
    for (int jj = 0; jj < 4; ++jj) nj[jj] = nt[(long)d * Nn + tid + 256 * jj];
#pragma unroll
    for (int r = 0; r < 4; ++r) {
      const float s = ni[r][d];
#pragma unroll
      for (int jj = 0; jj < 4; ++jj) acc[r][jj] = fmaf(s, nj[jj], acc[r][jj]);
    }
  }
  float sum = 0.f;
#pragma unroll
  for (int r = 0; r < 4; ++r)
#pragma unroll
    for (int jj = 0; jj < 4; ++jj) {
      const float d2 = nnorm[i0 + r] + nnorm[tid + 256 * jj] - 2.f * acc[r][jj];
      sum += sqrtf(fmaxf(d2, 0.f));
    }
  const float tot = block_reduce_sum(sum, sb);
  if (tid == 0) atomicAdd(&scal[1], tot);
}

__global__ __launch_bounds__(256) void k_dist_fb(
    const float* __restrict__ z, const float* __restrict__ nt,
    const float* __restrict__ nnorm, float* __restrict__ qout,
    float* __restrict__ srow, float* __restrict__ bmuf) {
  __shared__ float zt[Dd][65];
  __shared__ float rs4[4][64];
  __shared__ u64 cand[4][64];
  const int tid = threadIdx.x, lane = tid & 63, wave = tid >> 6;
  const long row0 = (long)blockIdx.x * 64;
  for (int k = 0; k < 64; ++k) {
    const int t = (int)((row0 + k) & (Tt - 1));
    const float tw = powf(0.9f, (float)(Tt - 1 - t));
    zt[tid][k] = z[(row0 + k) * Dd + tid] * tw;
  }
  __syncthreads();
  float zns = 0.f;
  for (int d = 0; d < Dd; ++d) {
    const float v = zt[d][lane];
    zns = fmaf(v, v, zns);
  }
  const long myrow = row0 + lane;
  float rsum = 0.f;
  u64 best = ~0ull;
  const int j0w = wave * 256;
  for (int chunk = 0; chunk < 16; ++chunk) {
    const int j0 = j0w + chunk * 16;
    float acc[16];
#pragma unroll
    for (int i = 0; i < 16; ++i) acc[i] = 0.f;
    const float* ntp = nt + j0;
    for (int d = 0; d < Dd; ++d) {
      const float zv = zt[d][lane];
      const float4 a = ((const float4*)ntp)[0];
      const float4 b = ((const float4*)ntp)[1];
      const float4 c = ((const float4*)ntp)[2];
      const float4 e = ((const float4*)ntp)[3];
      ntp += Nn;
      acc[0] = fmaf(zv, a.x, acc[0]); acc[1] = fmaf(zv, a.y, acc[1]);
      acc[2] = fmaf(zv, a.z, acc[2]); acc[3] = fmaf(zv, a.w, acc[3]);
      acc[4] = fmaf(zv, b.x, acc[4]); acc[5] = fmaf(zv, b.y, acc[5]);
      acc[6] = fmaf(zv, b.z, acc[6]); acc[7] = fmaf(zv, b.w, acc[7]);
      acc[8] = fmaf(zv, c.x, acc[8]); acc[9] = fmaf(zv, c.y, acc[9]);
      acc[10] = fmaf(zv, c.z, acc[10]); acc[11] = fmaf(zv, c.w, acc[11]);
      acc[12] = fmaf(zv, e.x, acc[12]); acc[13] = fmaf(zv, e.y, acc[13]);
      acc[14] = fmaf(zv, e.z, acc[14]); acc[15] = fmaf(zv, e.w, acc[15]);
    }
#pragma unroll
    for (int jj = 0; jj < 16; ++jj) {
      const int j = j0 + jj;
      const float d2 = zns + nnorm[j] - 2.f * acc[jj];
      const float dist = sqrtf(fmaxf(d2, 0.f));
      const float qr = 1.f / (1.f + dist);
      qout[myrow * Nn + j] = qr;
      rsum += qr;
      const u64 pk = ((u64)__float_as_uint(dist) << 32) | (unsigned int)j;
      best = pk < best ? pk : best;
    }
  }
  rs4[wave][lane] = rsum;
  cand[wave][lane] = best;
  __syncthreads();
  if (wave == 0) {
    const float s = rs4[0][lane] + rs4[1][lane] + rs4[2][lane] + rs4[3][lane];
    srow[myrow] = s;
    const u64 m0 = cand[0][lane] < cand[1][lane] ? cand[0][lane] : cand[1][lane];
    const u64 m1 = cand[2][lane] < cand[3][lane] ? cand[2][lane] : cand[3][lane];
    const u64 m = m0 < m1 ? m0 : m1;
    bmuf[myrow] = (float)(int)(unsigned int)(m & 0xffffffffull);
  }
}

__global__ __launch_bounds__(256) void k_norm_fb(float* __restrict__ q,
                                                 const float* __restrict__ srow,
                                                 float* __restrict__ colsum) {
  const int tid = threadIdx.x;
  const long r0 = (long)blockIdx.x * 16;
  float cs[4] = {0.f, 0.f, 0.f, 0.f};
  for (int r = 0; r < 16; ++r) {
    const long row = r0 + r;
    const float inv = 1.f / srow[row];
#pragma unroll
    for (int j = 0; j < 4; ++j) {
      const long idx = row * Nn + tid + 256 * j;
      const float v = q[idx] * inv;
      q[idx] = v;
      cs[j] = fmaf(v, v, cs[j]);
    }
  }
#pragma unroll
  for (int j = 0; j < 4; ++j) atomicAdd(&colsum[tid + 256 * j], cs[j]);
}

extern "C" void kernel_launch(void* const* d_in, const int* in_sizes, int n_in,
                              void* d_out, int out_size, void* d_ws, size_t ws_size,
                              hipStream_t stream) {
  const float* z = (const float*)d_in[0];
  const float* nodes = (const float*)d_in[1];
  float* out = (float*)d_out;
  unsigned char* ws = (unsigned char*)d_ws;

  float* som = out + OUT_SOM;
  float* scal_out = out + OUT_SCAL;
  float* qout = out + OUT_Q;
  float* bmuf = out + OUT_BMU;

  const size_t NEED = 34742288;
  if (ws_size >= NEED) {
    ushortT* zhiF = (ushortT*)(ws + 0);
    ushortT* zloF = (ushortT*)(ws + 16777216);
    ushortT* nhiF = (ushortT*)(ws + 33554432);
    ushortT* nloF = (ushortT*)(ws + 34078720);
    float* zn = (float*)(ws + 34603008);
    float* nnorm = (float*)(ws + 34734080);
    float* colsum = (float*)(ws + 34738176);
    float* scal = (float*)(ws + 34742272);

    hipMemsetAsync(colsum, 0, 4096 + 16, stream);  // colsum + scal

    k_conv<<<1088, 256, 0, stream>>>(z, nodes, zhiF, zloF, zn, nhiF, nloF, nnorm);
    k_gemm2<<<1024, 512, 0, stream>>>(zhiF, zloF, nhiF, nloF, zn, nnorm, qout, bmuf, colsum);
    k_div2<<<64, 256, 0, stream>>>(nhiF, nloF, nnorm, scal);
    k_kl<<<2048, 256, 0, stream>>>(qout, colsum, scal);
    k_somnb<<<2048, 256, 0, stream>>>(z, nodes, bmuf, som, scal);
    k_final<<<1, 1, 0, stream>>>(scal, scal_out);
  } else {
    float* wsf = (float*)ws;
    float* nt = wsf;
    float* nnorm = wsf + 262144;
    float* srow = wsf + 263168;
    float* colsum = wsf + 295936;
    float* scal = wsf + 296960;

    hipMemsetAsync(colsum, 0, (1024 + 4) * sizeof(float), stream);
    k_prep_fb<<<1024, 256, 0, stream>>>(nodes, nt, nnorm);
    k_div_fb<<<256, 256, 0, stream>>>(nodes, nt, nnorm, scal);
    k_dist_fb<<<512, 256, 0, stream>>>(z, nt, nnorm, qout, srow, bmuf);
    k_norm_fb<<<2048, 256, 0, stream>>>(qout, srow, colsum);
    k_kl<<<2048, 256, 0, stream>>>(qout, colsum, scal);
    k_somnb<<<2048, 256, 0, stream>>>(z, nodes, bmuf, som, scal);
    k_final<<<1, 1, 0, stream>>>(scal, scal_out);
  }
}

// Round 5
// 249.907 us; speedup vs baseline: 4.4744x; 1.1106x over previous
//
#include <hip/hip_runtime.h>
#include <math.h>

#define Bb 64
#define Tt 512
#define Dd 256
#define Nn 1024
#define NROWS 32768

// d_out layout (floats)
#define OUT_SOM 0L
#define OUT_SCAL 8388608L
#define OUT_Q 8388613L
#define OUT_BMU 41943045L

typedef __attribute__((ext_vector_type(8))) short bf16x8;
typedef __attribute__((ext_vector_type(4))) float f32x4;
typedef unsigned long long u64;
typedef unsigned short ushortT;

static __device__ __forceinline__ unsigned short f2bf(float x) {
  unsigned int u = __float_as_uint(x);
  unsigned int r = (u + 0x7fffu + ((u >> 16) & 1u)) >> 16;
  return (unsigned short)r;
}
static __device__ __forceinline__ float bf2f(unsigned short b) {
  return __uint_as_float(((unsigned int)b) << 16);
}

static __device__ __forceinline__ float block_reduce_sum(float v, float* sb) {
#pragma unroll
  for (int o = 32; o > 0; o >>= 1) v += __shfl_down(v, o, 64);
  const int lane = threadIdx.x & 63, w = threadIdx.x >> 6;
  if (lane == 0) sb[w] = v;
  __syncthreads();
  return (threadIdx.x == 0) ? (sb[0] + sb[1] + sb[2] + sb[3]) : 0.0f;
}

// ============ k_conv: build MFMA-fragment layouts ============
// A-frag (z): per 32-row tile rt: bf16 idx = ((ks*2+g)*4+k8)*128 + r16*8 + e
// B-frag (nodes): per 16-col tile ct: idx = ks*512 + k8*128 + c16*8 + e.
__global__ __launch_bounds__(256) void k_conv(
    const float* __restrict__ z, const float* __restrict__ nodes,
    ushortT* __restrict__ zhiF, ushortT* __restrict__ zloF, float* __restrict__ zn,
    ushortT* __restrict__ nhiF, ushortT* __restrict__ nloF, float* __restrict__ nnorm) {
  __shared__ float sm[32 * 260];
  const int tid = threadIdx.x;
  if (blockIdx.x < 1024) {
    const int rt = blockIdx.x;
    const long row0 = (long)rt * 32;
    const int r = tid >> 3, c8 = tid & 7;
    const long rowg = row0 + r;
    const int t = (int)(rowg & (Tt - 1));
    const float tw = powf(0.9f, (float)(Tt - 1 - t));
    float nrm = 0.f;
#pragma unroll
    for (int k = 0; k < 8; ++k) {
      const int c4 = c8 + k * 8;
      float4 v = ((const float4*)(z + rowg * Dd))[c4];
      v.x *= tw; v.y *= tw; v.z *= tw; v.w *= tw;
      *(float4*)&sm[r * 260 + c4 * 4] = v;
      nrm += v.x * v.x + v.y * v.y + v.z * v.z + v.w * v.w;
    }
    nrm += __shfl_xor(nrm, 1, 64);
    nrm += __shfl_xor(nrm, 2, 64);
    nrm += __shfl_xor(nrm, 4, 64);
    if (c8 == 0) zn[rowg] = nrm;
    __syncthreads();
    ushort4* oh = (ushort4*)(zhiF + (long)rt * 8192);
    ushort4* ol = (ushort4*)(zloF + (long)rt * 8192);
#pragma unroll
    for (int i = 0; i < 8; ++i) {
      const int o4 = tid + 256 * i;
      const int e4 = (o4 & 1) * 4;
      const int r16 = (o4 >> 1) & 15;
      const int k8 = (o4 >> 5) & 3;
      const int g = (o4 >> 7) & 1;
      const int ks = o4 >> 8;
      const float* p = &sm[(g * 16 + r16) * 260 + ks * 32 + k8 * 8 + e4];
      const float4 v = *(const float4*)p;
      ushort4 h, l;
      h.x = f2bf(v.x); l.x = f2bf(v.x - bf2f(h.x));
      h.y = f2bf(v.y); l.y = f2bf(v.y - bf2f(h.y));
      h.z = f2bf(v.z); l.z = f2bf(v.z - bf2f(h.z));
      h.w = f2bf(v.w); l.w = f2bf(v.w - bf2f(h.w));
      oh[o4] = h;
      ol[o4] = l;
    }
  } else {
    const int ct = blockIdx.x - 1024;  // 0..63
    const int jr = tid >> 4, cg = tid & 15;
    const long nrow = (long)(ct * 16 + jr);
    float nrm = 0.f;
#pragma unroll
    for (int k = 0; k < 4; ++k) {
      const int c4 = cg + k * 16;
      const float4 v = ((const float4*)(nodes + nrow * Dd))[c4];
      *(float4*)&sm[jr * 260 + c4 * 4] = v;
      nrm += v.x * v.x + v.y * v.y + v.z * v.z + v.w * v.w;
    }
    nrm += __shfl_xor(nrm, 1, 64);
    nrm += __shfl_xor(nrm, 2, 64);
    nrm += __shfl_xor(nrm, 4, 64);
    nrm += __shfl_xor(nrm, 8, 64);
    if (cg == 0) nnorm[nrow] = nrm;
    __syncthreads();
    ushort4* oh = (ushort4*)(nhiF + (long)ct * 4096);
    ushort4* ol = (ushort4*)(nloF + (long)ct * 4096);
#pragma unroll
    for (int i = 0; i < 4; ++i) {
      const int o4 = tid + 256 * i;
      const int e4 = (o4 & 1) * 4;
      const int c16 = (o4 >> 1) & 15;
      const int k8 = (o4 >> 5) & 3;
      const int ks = o4 >> 7;
      const float* p = &sm[c16 * 260 + ks * 32 + k8 * 8 + e4];
      const float4 v = *(const float4*)p;
      ushort4 h, l;
      h.x = f2bf(v.x); l.x = f2bf(v.x - bf2f(h.x));
      h.y = f2bf(v.y); l.y = f2bf(v.y - bf2f(h.y));
      h.z = f2bf(v.z); l.z = f2bf(v.z - bf2f(h.z));
      h.w = f2bf(v.w); l.w = f2bf(v.w - bf2f(h.w));
      oh[o4] = h;
      ol[o4] = l;
    }
  }
}

// ============ k_gemm3: 64x1024 per block, B-reg reuse across 2 row-groups ============
__global__ __launch_bounds__(512, 2) void k_gemm3(
    const ushortT* __restrict__ zhiF, const ushortT* __restrict__ zloF,
    const ushortT* __restrict__ nhiF, const ushortT* __restrict__ nloF,
    const float* __restrict__ zn, const float* __restrict__ nn,
    float* __restrict__ qout, float* __restrict__ bmuf, float* __restrict__ colsum) {
  __shared__ float srowS[64][8];
  __shared__ u64 sbmu[64][8];
  __shared__ float sinv[64];
  const int tid = threadIdx.x, lane = tid & 63, w = tid >> 6;
  const int rl = lane & 15, kq = lane >> 4;
  const long row0 = (long)blockIdx.x * 64;

  const ushortT* Ah0 = zhiF + (long)blockIdx.x * 16384;
  const ushortT* Al0 = zloF + (long)blockIdx.x * 16384;
  const ushortT* Bh = nhiF + (long)w * 8 * 4096;
  const ushortT* Bl = nloF + (long)w * 8 * 4096;
  const int lo8 = lane * 8;

  f32x4 acc[2][2][8];
#pragma unroll
  for (int rg = 0; rg < 2; ++rg)
#pragma unroll
    for (int g = 0; g < 2; ++g)
#pragma unroll
      for (int c = 0; c < 8; ++c) acc[rg][g][c] = (f32x4){0.f, 0.f, 0.f, 0.f};

#pragma unroll 1
  for (int ks = 0; ks < 8; ++ks) {
    bf16x8 ah[2][2], al[2][2];
#pragma unroll
    for (int rg = 0; rg < 2; ++rg)
#pragma unroll
      for (int g = 0; g < 2; ++g) {
        ah[rg][g] = *(const bf16x8*)(Ah0 + rg * 8192 + (ks * 2 + g) * 512 + lo8);
        al[rg][g] = *(const bf16x8*)(Al0 + rg * 8192 + (ks * 2 + g) * 512 + lo8);
      }
#pragma unroll
    for (int c = 0; c < 8; ++c) {
      const bf16x8 bh = *(const bf16x8*)(Bh + c * 4096 + ks * 512 + lo8);
      const bf16x8 bl = *(const bf16x8*)(Bl + c * 4096 + ks * 512 + lo8);
      __builtin_amdgcn_s_setprio(1);
#pragma unroll
      for (int rg = 0; rg < 2; ++rg)
#pragma unroll
        for (int g = 0; g < 2; ++g) {
          acc[rg][g][c] = __builtin_amdgcn_mfma_f32_16x16x32_bf16(ah[rg][g], bh, acc[rg][g][c], 0, 0, 0);
          acc[rg][g][c] = __builtin_amdgcn_mfma_f32_16x16x32_bf16(ah[rg][g], bl, acc[rg][g][c], 0, 0, 0);
          acc[rg][g][c] = __builtin_amdgcn_mfma_f32_16x16x32_bf16(al[rg][g], bh, acc[rg][g][c], 0, 0, 0);
        }
      __builtin_amdgcn_s_setprio(0);
    }
  }

  // ---- epilogue: dist -> q, per-row sum + argmin ----
  float nnv[8];
#pragma unroll
  for (int c = 0; c < 8; ++c) nnv[c] = nn[w * 128 + c * 16 + rl];

#pragma unroll
  for (int rg = 0; rg < 2; ++rg) {
    float rs[2][4];
    u64 bm[2][4];
#pragma unroll
    for (int g = 0; g < 2; ++g)
#pragma unroll
      for (int r = 0; r < 4; ++r) {
        rs[g][r] = 0.f;
        bm[g][r] = ~0ull;
      }
#pragma unroll
    for (int g = 0; g < 2; ++g) {
      float znv[4];
#pragma unroll
      for (int r = 0; r < 4; ++r) znv[r] = zn[row0 + rg * 32 + g * 16 + kq * 4 + r];
#pragma unroll
      for (int c = 0; c < 8; ++c)
#pragma unroll
        for (int r = 0; r < 4; ++r) {
          const float dot = acc[rg][g][c][r];
          const float d2 = znv[r] + nnv[c] - 2.f * dot;
          const float dist = sqrtf(fmaxf(d2, 0.f));
          const float qv = 1.f / (1.f + dist);
          acc[rg][g][c][r] = qv;
          rs[g][r] += qv;
          const int col = w * 128 + c * 16 + rl;
          const u64 pk = ((u64)__float_as_uint(dist) << 32) | (unsigned int)col;
          bm[g][r] = pk < bm[g][r] ? pk : bm[g][r];
        }
    }
#pragma unroll
    for (int g = 0; g < 2; ++g)
#pragma unroll
      for (int r = 0; r < 4; ++r) {
#pragma unroll
        for (int m = 1; m < 16; m <<= 1) {
          rs[g][r] += __shfl_xor(rs[g][r], m, 64);
          const u64 o = __shfl_xor(bm[g][r], m, 64);
          bm[g][r] = o < bm[g][r] ? o : bm[g][r];
        }
        if (rl == 0) {
          srowS[rg * 32 + g * 16 + kq * 4 + r][w] = rs[g][r];
          sbmu[rg * 32 + g * 16 + kq * 4 + r][w] = bm[g][r];
        }
      }
  }
  __syncthreads();
  if (tid < 64) {
    float s = 0.f;
    u64 best = ~0ull;
#pragma unroll
    for (int i = 0; i < 8; ++i) {
      s += srowS[tid][i];
      const u64 v = sbmu[tid][i];
      best = v < best ? v : best;
    }
    sinv[tid] = 1.f / s;
    bmuf[row0 + tid] = (float)(int)(unsigned int)(best & 0xffffffffull);
  }
  __syncthreads();

  // ---- normalize + store + colsum partials ----
  float cp[8];
#pragma unroll
  for (int c = 0; c < 8; ++c) cp[c] = 0.f;
#pragma unroll
  for (int rg = 0; rg < 2; ++rg)
#pragma unroll
    for (int g = 0; g < 2; ++g) {
      float inv[4];
#pragma unroll
      for (int r = 0; r < 4; ++r) inv[r] = sinv[rg * 32 + g * 16 + kq * 4 + r];
#pragma unroll
      for (int c = 0; c < 8; ++c)
#pragma unroll
        for (int r = 0; r < 4; ++r) {
          const float qn = acc[rg][g][c][r] * inv[r];
          qout[(row0 + rg * 32 + g * 16 + kq * 4 + r) * Nn + w * 128 + c * 16 + rl] = qn;
          cp[c] = fmaf(qn, qn, cp[c]);
        }
    }
#pragma unroll
  for (int c = 0; c < 8; ++c) {
    cp[c] += __shfl_xor(cp[c], 16, 64);
    cp[c] += __shfl_xor(cp[c], 32, 64);
    if (kq == 0) atomicAdd(&colsum[w * 128 + c * 16 + rl], cp[c]);
  }
}

// ============ k_div2: diversity via node fragments, col-split grid 256 ============
__global__ __launch_bounds__(256) void k_div2(
    const ushortT* __restrict__ nhiF, const ushortT* __restrict__ nloF,
    const float* __restrict__ nnorm, float* __restrict__ scal) {
  __shared__ float sb[4];
  const int tid = threadIdx.x, lane = tid & 63, w = tid >> 6;
  const int rl = lane & 15, kq = lane >> 4;
  const int bi = blockIdx.x & 63;   // 16-row tile of A
  const int cq = blockIdx.x >> 6;   // col quarter
  const int lo8 = lane * 8;

  f32x4 acc[4];
#pragma unroll
  for (int c = 0; c < 4; ++c) acc[c] = (f32x4){0.f, 0.f, 0.f, 0.f};

#pragma unroll 1
  for (int ks = 0; ks < 8; ++ks) {
    const bf16x8 ah = *(const bf16x8*)(nhiF + (long)bi * 4096 + ks * 512 + lo8);
    const bf16x8 al = *(const bf16x8*)(nloF + (long)bi * 4096 + ks * 512 + lo8);
#pragma unroll
    for (int c = 0; c < 4; ++c) {
      const long ct = (long)(cq * 16 + w * 4 + c);
      const bf16x8 bh = *(const bf16x8*)(nhiF + ct * 4096 + ks * 512 + lo8);
      const bf16x8 bl = *(const bf16x8*)(nloF + ct * 4096 + ks * 512 + lo8);
      acc[c] = __builtin_amdgcn_mfma_f32_16x16x32_bf16(ah, bh, acc[c], 0, 0, 0);
      acc[c] = __builtin_amdgcn_mfma_f32_16x16x32_bf16(ah, bl, acc[c], 0, 0, 0);
      acc[c] = __builtin_amdgcn_mfma_f32_16x16x32_bf16(al, bh, acc[c], 0, 0, 0);
    }
  }
  float ni[4];
#pragma unroll
  for (int r = 0; r < 4; ++r) ni[r] = nnorm[bi * 16 + kq * 4 + r];
  float dsum = 0.f;
#pragma unroll
  for (int c = 0; c < 4; ++c) {
    const float nj = nnorm[(cq * 16 + w * 4 + c) * 16 + rl];
#pragma unroll
    for (int r = 0; r < 4; ++r) {
      const float d2 = ni[r] + nj - 2.f * acc[c][r];
      dsum += sqrtf(fmaxf(d2, 0.f));
    }
  }
  const float tot = block_reduce_sum(dsum, sb);
  if (tid == 0) atomicAdd(&scal[1], tot);
}

// ============ k_kl: p + KL (1 log per element) ============
__global__ __launch_bounds__(256) void k_kl(const float* __restrict__ q,
                                            const float* __restrict__ colsum,
                                            float* __restrict__ scal) {
  __shared__ float rcs[Nn];
  __shared__ float lcs[Nn];
  __shared__ float sb[4];
  const int tid = threadIdx.x, lane = tid & 63, wave = tid >> 6;
#pragma unroll
  for (int j = 0; j < 4; ++j) {
    const float cs = colsum[tid + 256 * j];
    rcs[tid + 256 * j] = 1.f / cs;
    lcs[tid + 256 * j] = __logf(cs);
  }
  __syncthreads();
  const long r0 = (long)blockIdx.x * 16;
  float klp = 0.f;
  for (int rr = 0; rr < 4; ++rr) {
    const long row = r0 + rr * 4 + wave;
    float s = 0.f, a = 0.f;
#pragma unroll
    for (int j = 0; j < 16; ++j) {
      const int col = lane + 64 * j;
      const float t = q[row * Nn + col];
      const float u = t * t * rcs[col];
      s += u;
      a = fmaf(u, __logf(t) - lcs[col], a);
    }
#pragma unroll
    for (int o = 1; o < 64; o <<= 1) {
      s += __shfl_xor(s, o, 64);
      a += __shfl_xor(a, o, 64);
    }
    if (lane == 0) klp += a / s - __logf(s);  // once per row
  }
  const float tot = block_reduce_sum(klp, sb);
  if (tid == 0) atomicAdd(&scal[0], tot);
}

// ============ k_som + neighbor ============
__global__ __launch_bounds__(256) void k_somnb(const float* __restrict__ z,
                                               const float* __restrict__ nodes,
                                               const float* __restrict__ bmuf,
                                               float* __restrict__ som,
                                               float* __restrict__ scal) {
  __shared__ float sb[4];
  const int tid = threadIdx.x;
  const long r0 = (long)blockIdx.x * 16;
  float ts = 0.f, zp = 0.f;
  if ((r0 & (Tt - 1)) > 0) zp = z[(r0 - 1) * Dd + tid];
  for (int r = 0; r < 16; ++r) {
    const long row = r0 + r;
    const float zc = z[row * Dd + tid];
    const int bi = (int)bmuf[row];
    const float nv = nodes[(long)bi * Dd + tid];
    som[row * Dd + tid] = zc + 0.1f * (nv - zc);
    if ((row & (Tt - 1)) > 0) {
      const float dd = zc - zp;
      ts = fmaf(dd, dd, ts);
    }
    zp = zc;
  }
  const float tts = block_reduce_sum(ts, sb);
  if (tid == 0) atomicAdd(&scal[2], tts);
  float nbv = 0.f;
  if (tid < 16) {
    const long row = r0 + tid;
    if ((row & (Tt - 1)) != (Tt - 1)) {
      const int b1 = (int)bmuf[row], b2 = (int)bmuf[row + 1];
      nbv = (float)(abs((b1 >> 5) - (b2 >> 5)) + abs((b1 & 31) - (b2 & 31)));
    }
  }
  __syncthreads();
  const float tnb = block_reduce_sum(nbv, sb);
  if (tid == 0) atomicAdd(&scal[3], tnb);
}

// ---- final scalars ----
__global__ void k_final(const float* __restrict__ scal, float* __restrict__ o) {
  const float kl = scal[0] * (1.f / 32768.f);
  const float dv = -scal[1] * (1.f / (1024.f * 1024.f));
  const float ts = scal[2] * (0.9f / (64.f * 511.f * 256.f));
  const float nb = scal[3] * (1.f / 32704.f);
  o[0] = kl + 0.5f * dv + 0.3f * ts + 0.2f * nb;
  o[1] = kl;
  o[2] = dv;
  o[3] = ts;
  o[4] = nb;
}

// ================= fallback (fp32 path, small ws) =================
__global__ __launch_bounds__(256) void k_prep_fb(const float* __restrict__ nodes,
                                                 float* __restrict__ nt,
                                                 float* __restrict__ nnorm) {
  __shared__ float sb[4];
  const int j = blockIdx.x, d = threadIdx.x;
  const float v = nodes[j * Dd + d];
  nt[(long)d * Nn + j] = v;
  const float tot = block_reduce_sum(v * v, sb);
  if (threadIdx.x == 0) nnorm[j] = tot;
}

__global__ __launch_bounds__(256) void k_div_fb(const float* __restrict__ nodes,
                                                const float* __restrict__ nt,
                                                const float* __restrict__ nnorm,
                                                float* __restrict__ scal) {
  __shared__ float ni[4][Dd];
  __shared__ float sb[4];
  const int tid = threadIdx.x;
  const int i0 = blockIdx.x * 4;
#pragma unroll
  for (int r = 0; r < 4; ++r) ni[r][tid] = nodes[(i0 + r) * Dd + tid];
  __syncthreads();
  float acc[4][4];
#pragma unroll
  for (int r = 0; r < 4; ++r)
#pragma unroll
    for (int jj = 0; jj < 4; ++jj) acc[r][jj] = 0.f;
  for (int d = 0; d < Dd; ++d) {
    float nj[4];
#pragma unroll
    for (int jj = 0; jj < 4; ++jj) nj[jj] = nt[(long)d * Nn + tid + 256 * jj];
#pragma unroll
    for (int r = 0; r < 4; ++r) {
      const float s = ni[r][d];
#pragma unroll
      for (int jj = 0; jj < 4; ++jj) acc[r][jj] = fmaf(s, nj[jj], acc[r][jj]);
    }
  }
  float sum = 0.f;
#pragma unroll
  for (int r = 0; r < 4; ++r)
#pragma unroll
    for (int jj = 0; jj < 4; ++jj) {
      const float d2 = nnorm[i0 + r] + nnorm[tid + 256 * jj] - 2.f * acc[r][jj];
      sum += sqrtf(fmaxf(d2, 0.f));
    }
  const float tot = block_reduce_sum(sum, sb);
  if (tid == 0) atomicAdd(&scal[1], tot);
}

__global__ __launch_bounds__(256) void k_dist_fb(
    const float* __restrict__ z, const float* __restrict__ nt,
    const float* __restrict__ nnorm, float* __restrict__ qout,
    float* __restrict__ srow, float* __restrict__ bmuf) {
  __shared__ float zt[Dd][65];
  __shared__ float rs4[4][64];
  __shared__ u64 cand[4][64];
  const int tid = threadIdx.x, lane = tid & 63, wave = tid >> 6;
  const long row0 = (long)blockIdx.x * 64;
  for (int k = 0; k < 64; ++k) {
    const int t = (int)((row0 + k) & (Tt - 1));
    const float tw = powf(0.9f, (float)(Tt - 1 - t));
    zt[tid][k] = z[(row0 + k) * Dd + tid] * tw;
  }
  __syncthreads();
  float zns = 0.f;
  for (int d = 0; d < Dd; ++d) {
    const float v = zt[d][lane];
    zns = fmaf(v, v, zns);
  }
  const long myrow = row0 + lane;
  float rsum = 0.f;
  u64 best = ~0ull;
  const int j0w = wave * 256;
  for (int chunk = 0; chunk < 16; ++chunk) {
    const int j0 = j0w + chunk * 16;
    float acc[16];
#pragma unroll
    for (int i = 0; i < 16; ++i) acc[i] = 0.f;
    const float* ntp = nt + j0;
    for (int d = 0; d < Dd; ++d) {
      const float zv = zt[d][lane];
      const float4 a = ((const float4*)ntp)[0];
      const float4 b = ((const float4*)ntp)[1];
      const float4 c = ((const float4*)ntp)[2];
      const float4 e = ((const float4*)ntp)[3];
      ntp += Nn;
      acc[0] = fmaf(zv, a.x, acc[0]); acc[1] = fmaf(zv, a.y, acc[1]);
      acc[2] = fmaf(zv, a.z, acc[2]); acc[3] = fmaf(zv, a.w, acc[3]);
      acc[4] = fmaf(zv, b.x, acc[4]); acc[5] = fmaf(zv, b.y, acc[5]);
      acc[6] = fmaf(zv, b.z, acc[6]); acc[7] = fmaf(zv, b.w, acc[7]);
      acc[8] = fmaf(zv, c.x, acc[8]); acc[9] = fmaf(zv, c.y, acc[9]);
      acc[10] = fmaf(zv, c.z, acc[10]); acc[11] = fmaf(zv, c.w, acc[11]);
      acc[12] = fmaf(zv, e.x, acc[12]); acc[13] = fmaf(zv, e.y, acc[13]);
      acc[14] = fmaf(zv, e.z, acc[14]); acc[15] = fmaf(zv, e.w, acc[15]);
    }
#pragma unroll
    for (int jj = 0; jj < 16; ++jj) {
      const int j = j0 + jj;
      const float d2 = zns + nnorm[j] - 2.f * acc[jj];
      const float dist = sqrtf(fmaxf(d2, 0.f));
      const float qr = 1.f / (1.f + dist);
      qout[myrow * Nn + j] = qr;
      rsum += qr;
      const u64 pk = ((u64)__float_as_uint(dist) << 32) | (unsigned int)j;
      best = pk < best ? pk : best;
    }
  }
  rs4[wave][lane] = rsum;
  cand[wave][lane] = best;
  __syncthreads();
  if (wave == 0) {
    const float s = rs4[0][lane] + rs4[1][lane] + rs4[2][lane] + rs4[3][lane];
    srow[myrow] = s;
    const u64 m0 = cand[0][lane] < cand[1][lane] ? cand[0][lane] : cand[1][lane];
    const u64 m1 = cand[2][lane] < cand[3][lane] ? cand[2][lane] : cand[3][lane];
    const u64 m = m0 < m1 ? m0 : m1;
    bmuf[myrow] = (float)(int)(unsigned int)(m & 0xffffffffull);
  }
}

__global__ __launch_bounds__(256) void k_norm_fb(float* __restrict__ q,
                                                 const float* __restrict__ srow,
                                                 float* __restrict__ colsum) {
  const int tid = threadIdx.x;
  const long r0 = (long)blockIdx.x * 16;
  float cs[4] = {0.f, 0.f, 0.f, 0.f};
  for (int r = 0; r < 16; ++r) {
    const long row = r0 + r;
    const float inv = 1.f / srow[row];
#pragma unroll
    for (int j = 0; j < 4; ++j) {
      const long idx = row * Nn + tid + 256 * j;
      const float v = q[idx] * inv;
      q[idx] = v;
      cs[j] = fmaf(v, v, cs[j]);
    }
  }
#pragma unroll
  for (int j = 0; j < 4; ++j) atomicAdd(&colsum[tid + 256 * j], cs[j]);
}

extern "C" void kernel_launch(void* const* d_in, const int* in_sizes, int n_in,
                              void* d_out, int out_size, void* d_ws, size_t ws_size,
                              hipStream_t stream) {
  const float* z = (const float*)d_in[0];
  const float* nodes = (const float*)d_in[1];
  float* out = (float*)d_out;
  unsigned char* ws = (unsigned char*)d_ws;

  float* som = out + OUT_SOM;
  float* scal_out = out + OUT_SCAL;
  float* qout = out + OUT_Q;
  float* bmuf = out + OUT_BMU;

  const size_t NEED = 34742288;
  if (ws_size >= NEED) {
    ushortT* zhiF = (ushortT*)(ws + 0);
    ushortT* zloF = (ushortT*)(ws + 16777216);
    ushortT* nhiF = (ushortT*)(ws + 33554432);
    ushortT* nloF = (ushortT*)(ws + 34078720);
    float* zn = (float*)(ws + 34603008);
    float* nnorm = (float*)(ws + 34734080);
    float* colsum = (float*)(ws + 34738176);
    float* scal = (float*)(ws + 34742272);

    hipMemsetAsync(colsum, 0, 4096 + 16, stream);  // colsum + scal

    k_conv<<<1088, 256, 0, stream>>>(z, nodes, zhiF, zloF, zn, nhiF, nloF, nnorm);
    k_gemm3<<<512, 512, 0, stream>>>(zhiF, zloF, nhiF, nloF, zn, nnorm, qout, bmuf, colsum);
    k_div2<<<256, 256, 0, stream>>>(nhiF, nloF, nnorm, scal);
    k_kl<<<2048, 256, 0, stream>>>(qout, colsum, scal);
    k_somnb<<<2048, 256, 0, stream>>>(z, nodes, bmuf, som, scal);
    k_final<<<1, 1, 0, stream>>>(scal, scal_out);
  } else {
    float* wsf = (float*)ws;
    float* nt = wsf;
    float* nnorm = wsf + 262144;
    float* srow = wsf + 263168;
    float* colsum = wsf + 295936;
    float* scal = wsf + 296960;

    hipMemsetAsync(colsum, 0, (1024 + 4) * sizeof(float), stream);
    k_prep_fb<<<1024, 256, 0, stream>>>(nodes, nt, nnorm);
    k_div_fb<<<256, 256, 0, stream>>>(nodes, nt, nnorm, scal);
    k_dist_fb<<<512, 256, 0, stream>>>(z, nt, nnorm, qout, srow, bmuf);
    k_norm_fb<<<2048, 256, 0, stream>>>(qout, srow, colsum);
    k_kl<<<2048, 256, 0, stream>>>(qout, colsum, scal);
    k_somnb<<<2048, 256, 0, stream>>>(z, nodes, bmuf, som, scal);
    k_final<<<1, 1, 0, stream>>>(scal, scal_out);
  }
}